// Round 11
// baseline (852.735 us; speedup 1.0000x reference)
//
#include <hip/hip_runtime.h>
#include <hip/hip_fp16.h>

#define NN    20000
#define NE    150000
#define HD    256
#define NT    4
#define NR    8
#define NH    8
#define DKq   32
#define NL    2
#define MAXL  240
#define HBLK  256
#define SCB   ((NN + 255)/256)
#define RT64  ((NN + 63)/64)          // 313 row tiles
#define TTILES (RT64*NT)              // 1252
#define INV_SQRT_DK 0.17677669529663687f

typedef _Float16 f16x4 __attribute__((ext_vector_type(4)));
typedef float    f32x4v __attribute__((ext_vector_type(4)));

// ---------- node bucketing (by type), block-local histogram ----------
__global__ __launch_bounds__(256) void k_nhist(const int* __restrict__ ntype, int* __restrict__ nhist)
{
    __shared__ int h[NT];
    const int tid = threadIdx.x, b = blockIdx.x;
    if (tid < NT) h[tid] = 0;
    __syncthreads();
    const int cn = (NN + HBLK-1)/HBLK;
    const int nEnd = min((b+1)*cn, NN);
    for (int i = b*cn + tid; i < nEnd; i += 256) atomicAdd(&h[ntype[i]], 1);
    __syncthreads();
    if (tid < NT) nhist[b*NT + tid] = h[tid];
}
__global__ void k_nscan(const int* __restrict__ nhist, int* __restrict__ noff, int* __restrict__ nbase)
{
    __shared__ int tot[NT];
    const int tid = threadIdx.x;
    if (tid < NT){
        int s = 0;
        for (int b = 0; b < HBLK; b++) s += nhist[b*NT + tid];
        tot[tid] = s;
    }
    __syncthreads();
    if (tid == 0){ noff[0]=0; for (int t=0;t<NT;t++) noff[t+1]=noff[t]+tot[t]; }
    if (tid < NT){
        int base = 0; for (int t=0;t<tid;t++) base += tot[t];
        int run = 0;
        for (int b=0;b<HBLK;b++){ nbase[b*NT+tid] = base + run; run += nhist[b*NT+tid]; }
    }
}
__global__ __launch_bounds__(256) void k_nscatter(const int* __restrict__ ntype,
    const int* __restrict__ nbase, int* __restrict__ nbucket)
{
    __shared__ int cur[NT];
    const int tid = threadIdx.x, b = blockIdx.x;
    if (tid < NT) cur[tid] = nbase[b*NT + tid];
    __syncthreads();
    const int cn = (NN + HBLK-1)/HBLK;
    const int nEnd = min((b+1)*cn, NN);
    for (int i = b*cn + tid; i < nEnd; i += 256)
        nbucket[atomicAdd(&cur[ntype[i]], 1)] = i;
}

// ---------- edge CSR build: sort by tgt ----------
__global__ void k_zero_bins(int* __restrict__ cnt){
    int i = blockIdx.x*256 + threadIdx.x;
    if (i < NN) cnt[i] = 0;
}
__global__ void k_csr_hist(const int* __restrict__ ei, int* __restrict__ cnt){
    int e = blockIdx.x*256 + threadIdx.x;
    if (e >= NE) return;
    atomicAdd(&cnt[ei[NE+e]], 1);
}
__global__ __launch_bounds__(256) void k_scan1(const int* __restrict__ cnt,
    int* __restrict__ tgt_off, int* __restrict__ bsum)
{
    __shared__ int sh[256];
    const int t = threadIdx.x, b = blockIdx.x;
    const int i = b*256 + t;
    const int v = (i < NN) ? cnt[i] : 0;
    sh[t] = v;
    __syncthreads();
    #pragma unroll
    for (int d = 1; d < 256; d <<= 1){
        const int u = (t >= d) ? sh[t-d] : 0;
        __syncthreads();
        sh[t] += u;
        __syncthreads();
    }
    if (i < NN) tgt_off[i] = sh[t] - v;
    if (t == 255) bsum[b] = sh[255];
}
__global__ __launch_bounds__(128) void k_scan2(const int* __restrict__ bsum,
    int* __restrict__ bbase, int* __restrict__ tgt_off)
{
    __shared__ int sh[128];
    const int t = threadIdx.x;
    const int v = (t < SCB) ? bsum[t] : 0;
    sh[t] = v;
    __syncthreads();
    #pragma unroll
    for (int d = 1; d < 128; d <<= 1){
        const int u = (t >= d) ? sh[t-d] : 0;
        __syncthreads();
        sh[t] += u;
        __syncthreads();
    }
    if (t < SCB) bbase[t] = sh[t] - v;
    if (t == 0) tgt_off[NN] = NE;
}
__global__ __launch_bounds__(256) void k_scan3(int* __restrict__ tgt_off,
    const int* __restrict__ bbase, int* __restrict__ binCur)
{
    const int i = blockIdx.x*256 + threadIdx.x;
    if (i >= NN) return;
    const int o = tgt_off[i] + bbase[blockIdx.x];
    tgt_off[i] = o;
    binCur[i] = o;
}
__global__ void k_csr_scatter(const int* __restrict__ ei, const int* __restrict__ etype,
    const int* __restrict__ etime, const int* __restrict__ ntype,
    int* __restrict__ binCur, int* __restrict__ src_s, int* __restrict__ combo_s,
    int* __restrict__ eid_s, int* __restrict__ tgt_s)
{
    int e = blockIdx.x*256 + threadIdx.x;
    if (e >= NE) return;
    const int tgt = ei[NE+e], r = etype[e], src = ei[e];
    const int pos = atomicAdd(&binCur[tgt], 1);
    src_s[pos] = src;
    combo_s[pos] = (etime[e]*NT + ntype[src]) | (r << 12);
    eid_s[pos] = e;
    tgt_s[pos] = tgt;
}

// ---------- weight pre-pack: f32 [K][C] -> f16 fragment-major [(k>>2)*C + c][k&3] ----------
__global__ __launch_bounds__(256) void k_w2f16(
    const float* __restrict__ in, _Float16* __restrict__ out, int lc)
{
    const size_t msz = (size_t)gridDim.x * 1024;
    const float* ip = in + (size_t)blockIdx.y * msz;
    _Float16* op = out + (size_t)blockIdx.y * msz;
    const int tid4 = blockIdx.x*256 + threadIdx.x;
    const int C = 1 << lc;
    const int k4 = tid4 >> lc, c = tid4 & (C-1);
    f16x4 hv;
    #pragma unroll
    for (int j = 0; j < 4; j++)
        hv[j] = (_Float16)ip[(size_t)(((k4*4 + j) << lc) + c)];
    *reinterpret_cast<f16x4*>(&op[(size_t)tid4 * 4]) = hv;
}

// ---------- typed MFMA GEMM: wave owns 16 rows x 256 cols; A-frags in registers ----------
// A staged once to LDS; each wave reads its 16 rows ONCE (32 VGPRs of a-frags), then
// streams B-frags from the L2-resident frag-major table across 16 col-subtiles x nsel mats.
// grid = TTILES (1D). mode 0: bias; 1: tanh; 2: skip-combine.
__global__ __launch_bounds__(256) void k_typed_mfma(
    const float* __restrict__ in,
    const _Float16* __restrict__ W0, const _Float16* __restrict__ W1, const _Float16* __restrict__ W2,
    const float* __restrict__ b0, const float* __restrict__ b1, const float* __restrict__ b2,
    float* __restrict__ o0, float* __restrict__ o1, float* __restrict__ o2,
    const int* __restrict__ nbucket, const int* __restrict__ noff,
    int nsel, int mode, const float* __restrict__ skipv, const float* __restrict__ xold)
{
    const int T = blockIdx.x;
    const int t = T / RT64;
    const int rowTile = T - t*RT64;
    const int start = noff[t], cnt = noff[t+1] - start;
    if (rowTile*64 >= cnt) return;

    const int tid = threadIdx.x;
    const int w = tid >> 6, lane = tid & 63;
    const int lrow = lane & 15, lgrp = lane >> 4;

    __shared__ _Float16 Al[64][260];
    __shared__ int nid[64];

    if (tid < 64){
        const int gr = rowTile*64 + tid;
        nid[tid] = (gr < cnt) ? nbucket[start + gr] : -1;
    }
    __syncthreads();

    // stage A once (f32 -> f16)
    {
        const int arow = nid[tid & 63];
        const int cc0 = (tid >> 6)*64;
        const float* ap = (arow >= 0) ? (in + (size_t)arow*HD + cc0) : nullptr;
        #pragma unroll
        for (int kk = 0; kk < 16; kk++){
            float4 v = make_float4(0.f,0.f,0.f,0.f);
            if (ap) v = *reinterpret_cast<const float4*>(ap + kk*4);
            f16x4 hv;
            hv[0]=(_Float16)v.x; hv[1]=(_Float16)v.y; hv[2]=(_Float16)v.z; hv[3]=(_Float16)v.w;
            *reinterpret_cast<f16x4*>(&Al[tid & 63][cc0 + kk*4]) = hv;
        }
    }
    __syncthreads();

    // wave w owns rows [w*16, w*16+16); a-frags read from LDS ONCE into registers
    f16x4 afr[16];
    #pragma unroll
    for (int kc = 0; kc < 16; kc++)
        afr[kc] = *reinterpret_cast<const f16x4*>(&Al[w*16 + lrow][kc*16 + lgrp*4]);

    float sk = 0.f;
    if (mode == 2) sk = 1.f/(1.f + __expf(-skipv[t]));

    auto proc = [&](const _Float16* Wb, const float* bb, float* out){
        const _Float16* W = Wb + (size_t)t*HD*HD;
        const float* bias = bb + (size_t)t*HD;
        #pragma unroll 1
        for (int cs = 0; cs < 16; cs++){
            const int col0 = cs*16;
            f16x4 bfrag[16];
            #pragma unroll
            for (int kc = 0; kc < 16; kc++)
                bfrag[kc] = *reinterpret_cast<const f16x4*>(
                    &W[(size_t)((kc*4 + lgrp)*HD + col0 + lrow)*4]);
            // two interleaved accumulators break the dependent MFMA chain
            f32x4v acc0 = {0.f,0.f,0.f,0.f}, acc1 = {0.f,0.f,0.f,0.f};
            #pragma unroll
            for (int kc = 0; kc < 16; kc += 2){
                acc0 = __builtin_amdgcn_mfma_f32_16x16x16f16(afr[kc+0], bfrag[kc+0], acc0, 0,0,0);
                acc1 = __builtin_amdgcn_mfma_f32_16x16x16f16(afr[kc+1], bfrag[kc+1], acc1, 0,0,0);
            }
            const int col = col0 + lrow;
            const float bcol = bias[col];
            #pragma unroll
            for (int i = 0; i < 4; i++){
                const int lr = w*16 + lgrp*4 + i;
                const int gr = rowTile*64 + lr;
                if (gr >= cnt) continue;
                const int node = nid[lr];
                float v = acc0[i] + acc1[i] + bcol;
                if (mode == 1) v = tanhf(v);
                else if (mode == 2){
                    const float xo = xold[(size_t)node*HD + col];
                    v = v*sk + xo*(1.f - sk);
                }
                out[(size_t)node*HD + col] = v;
            }
        }
    };

    proc(W0, b0, o0);
    if (nsel > 1){
        proc(W1, b1, o1);
        proc(W2, b2, o2);
    }
}

// ---------- small row GEMM: C[row, ty] = A[row] @ W[ty] (+bias) ----------
__global__ __launch_bounds__(256) void k_row_gemm(
    const float* __restrict__ A, const float* __restrict__ Wb, const float* __restrict__ bias,
    float* __restrict__ C, int c_stride)
{
    const int row = blockIdx.x, ty = blockIdx.y, d = threadIdx.x;
    const float* W = Wb + (size_t)ty*HD*HD;
    __shared__ float ar[HD];
    ar[d] = A[(size_t)row*HD + d];
    __syncthreads();
    float acc = bias ? bias[d] : 0.f;
    #pragma unroll 8
    for (int k=0;k<HD;k++) acc = fmaf(ar[k], W[(size_t)k*HD + d], acc);
    C[(size_t)row*c_stride + ty*HD + d] = acc;
}

// ---------- MFMA fold: OUT[m][r][h*32+c] = sum_d IN[m][h*32+d] * MAT[r][h][d][c] (fp16 out) ----------
__global__ __launch_bounds__(256) void k_fold_mfma(
    const float* __restrict__ IN, const _Float16* __restrict__ MATF,
    __half* __restrict__ OUT, int M)
{
    const int r = blockIdx.y;
    const int lane = threadIdx.x & 63, w = threadIdx.x >> 6;
    const int lrow = lane & 15, lgrp = lane >> 4;
    f16x4 b[NH][2][2];
    const _Float16* Mr = MATF + (size_t)r*NH*1024;
    #pragma unroll
    for (int h = 0; h < NH; h++)
      #pragma unroll
      for (int kb = 0; kb < 2; kb++)
        #pragma unroll
        for (int hf = 0; hf < 2; hf++)
            b[h][kb][hf] = *reinterpret_cast<const f16x4*>(
                &Mr[(size_t)h*1024 + (size_t)(((kb*4 + lgrp)*32) + hf*16 + lrow)*4]);
    const int ntiles = M >> 4;
    for (int t = blockIdx.x*4 + w; t < ntiles; t += gridDim.x*4){
        const int row0 = t*16;
        const float* inrow = IN + (size_t)(row0 + lrow)*HD;
        f16x4 a[NH][2];
        #pragma unroll
        for (int h = 0; h < NH; h++)
          #pragma unroll
          for (int kb = 0; kb < 2; kb++){
              const float4 v = *reinterpret_cast<const float4*>(&inrow[h*32 + kb*16 + lgrp*4]);
              f16x4 aa;
              aa[0]=(_Float16)v.x; aa[1]=(_Float16)v.y; aa[2]=(_Float16)v.z; aa[3]=(_Float16)v.w;
              a[h][kb] = aa;
          }
        #pragma unroll
        for (int h = 0; h < NH; h++){
          #pragma unroll
          for (int hf = 0; hf < 2; hf++){
              f32x4v acc = {0.f,0.f,0.f,0.f};
              acc = __builtin_amdgcn_mfma_f32_16x16x16f16(a[h][0], b[h][0][hf], acc, 0,0,0);
              acc = __builtin_amdgcn_mfma_f32_16x16x16f16(a[h][1], b[h][1][hf], acc, 0,0,0);
              #pragma unroll
              for (int i = 0; i < 4; i++){
                  const int rr = lgrp*4 + i;
                  OUT[((size_t)(row0+rr)*NR + r)*HD + h*32 + hf*16 + lrow] = __float2half(acc[i]);
              }
          }
        }
    }
}

// ---------- edge scores (streaming, wave per edge) ----------
__global__ __launch_bounds__(256) void k_score(
    const float* __restrict__ q0, const __half* __restrict__ kA, const __half* __restrict__ KcA,
    const float* __restrict__ relP,
    const int* __restrict__ src_s, const int* __restrict__ combo_s, const int* __restrict__ tgt_s,
    float* __restrict__ s_arr)
{
    const int j = blockIdx.x*4 + (threadIdx.x >> 6);
    if (j >= NE) return;
    const int lane = threadIdx.x & 63;
    const int h = lane >> 3, c4 = (lane & 7) << 2;
    const int src = src_s[j];
    const int cw  = combo_s[j];
    const int tgt = tgt_s[j];
    const int r = cw >> 12, combo = cw & 0xFFF;

    const float4 q4 = *reinterpret_cast<const float4*>(&q0[(size_t)tgt*HD + h*32 + c4]);
    const __half2* ka = reinterpret_cast<const __half2*>(&kA[((size_t)src*NR + r)*HD + h*32 + c4]);
    const __half2* kc = reinterpret_cast<const __half2*>(&KcA[((size_t)combo*NR + r)*HD + h*32 + c4]);
    const float2 k0f = __half22float2(ka[0]), k1f = __half22float2(ka[1]);
    const float2 c0f = __half22float2(kc[0]), c1f = __half22float2(kc[1]);
    float v = q4.x*(k0f.x+c0f.x) + q4.y*(k0f.y+c0f.y) + q4.z*(k1f.x+c1f.x) + q4.w*(k1f.y+c1f.y);
    v += __shfl_xor(v, 1); v += __shfl_xor(v, 2); v += __shfl_xor(v, 4);
    if ((lane & 7) == 0)
        s_arr[(size_t)j*NH + h] = v * relP[r*NH + h] * INV_SQRT_DK;
}

// ---------- node-parallel segment softmax (CSR) ----------
__global__ __launch_bounds__(256) void k_softmax(
    float* __restrict__ s_arr, const int* __restrict__ tgt_off, const int* __restrict__ eid_s,
    float* __restrict__ out_att, int store)
{
    const int idx = blockIdx.x*256 + threadIdx.x;
    if (idx >= NN*NH) return;
    const int n = idx >> 3, h = idx & 7;
    const int e0 = tgt_off[n], e1 = tgt_off[n+1];
    if (e0 == e1) return;
    float m = -INFINITY;
    for (int j = e0; j < e1; j++) m = fmaxf(m, s_arr[(size_t)j*NH + h]);
    float l = 0.f;
    for (int j = e0; j < e1; j++) l += __expf(s_arr[(size_t)j*NH + h] - m);
    const float inv = 1.f / l;
    for (int j = e0; j < e1; j++){
        const float a = __expf(s_arr[(size_t)j*NH + h] - m) * inv;
        s_arr[(size_t)j*NH + h] = a;
        if (store) out_att[(size_t)eid_s[j]*NH + h] = a;
    }
}

// ---------- aggregation (CSR, wave per node), gelu fused ----------
__global__ __launch_bounds__(256) void k_agg(
    const __half* __restrict__ vM, const __half* __restrict__ VcM,
    const float* __restrict__ alpha,
    const int* __restrict__ tgt_off, const int* __restrict__ src_s, const int* __restrict__ combo_s,
    float* __restrict__ agg)
{
    const int n = blockIdx.x*4 + (threadIdx.x >> 6);
    if (n >= NN) return;
    const int lane = threadIdx.x & 63;
    const int h = lane >> 3, c4 = (lane & 7) << 2;
    const int col = h*32 + c4;
    const int e0 = tgt_off[n], e1 = tgt_off[n+1];
    float a0=0.f, a1=0.f, a2=0.f, a3=0.f;
    for (int j = e0; j < e1; j++){
        const int src = src_s[j];
        const int cw  = combo_s[j];
        const int r = cw >> 12, combo = cw & 0xFFF;
        const float al = alpha[(size_t)j*NH + h];
        const __half2* vm = reinterpret_cast<const __half2*>(&vM[((size_t)src*NR + r)*HD + col]);
        const __half2* vc = reinterpret_cast<const __half2*>(&VcM[((size_t)combo*NR + r)*HD + col]);
        const float2 v0f = __half22float2(vm[0]), v1f = __half22float2(vm[1]);
        const float2 c0f = __half22float2(vc[0]), c1f = __half22float2(vc[1]);
        a0 = fmaf(al, v0f.x + c0f.x, a0);
        a1 = fmaf(al, v0f.y + c0f.y, a1);
        a2 = fmaf(al, v1f.x + c1f.x, a2);
        a3 = fmaf(al, v1f.y + c1f.y, a3);
    }
    float4 o;
    o.x = 0.5f*a0*(1.f + erff(a0*0.70710678118654752f));
    o.y = 0.5f*a1*(1.f + erff(a1*0.70710678118654752f));
    o.z = 0.5f*a2*(1.f + erff(a2*0.70710678118654752f));
    o.w = 0.5f*a3*(1.f + erff(a3*0.70710678118654752f));
    *reinterpret_cast<float4*>(&agg[(size_t)n*HD + col]) = o;
}

__global__ void k_copy(const float* __restrict__ s, float* __restrict__ d, int n){
    int i = blockIdx.x*256 + threadIdx.x;
    if (i < n) d[i] = s[i];
}

extern "C" void kernel_launch(void* const* d_in, const int* in_sizes, int n_in,
                              void* d_out, int out_size, void* d_ws, size_t ws_size,
                              hipStream_t stream)
{
    const float* node_feature = (const float*)d_in[0];
    const int*   node_type    = (const int*)d_in[1];
    const int*   edge_time    = (const int*)d_in[2];
    const int*   edge_index   = (const int*)d_in[3];
    const int*   edge_type    = (const int*)d_in[4];
    const float* adapt_W = (const float*)d_in[5];
    const float* adapt_b = (const float*)d_in[6];
    const float* k_W = (const float*)d_in[7];
    const float* k_b = (const float*)d_in[8];
    const float* q_W = (const float*)d_in[9];
    const float* q_b = (const float*)d_in[10];
    const float* v_W = (const float*)d_in[11];
    const float* v_b = (const float*)d_in[12];
    const float* a_W = (const float*)d_in[13];
    const float* a_b = (const float*)d_in[14];
    const float* rel_pri = (const float*)d_in[15];
    const float* rel_att = (const float*)d_in[16];
    const float* rel_msg = (const float*)d_in[17];
    const float* skip  = (const float*)d_in[18];
    const float* rte_W = (const float*)d_in[19];
    const float* rte_b = (const float*)d_in[20];
    const float* rte_emb = (const float*)d_in[21];

    char* wp = (char*)d_ws;
    auto alloc_f = [&](size_t n)->float*{ float* p=(float*)wp; wp += n*sizeof(float); return p; };
    auto alloc_i = [&](size_t n)->int*  { int*   p=(int*)wp;   wp += n*sizeof(int);   return p; };
    auto alloc_h = [&](size_t n)->_Float16*{ _Float16* p=(_Float16*)wp; wp += n*sizeof(_Float16); return p; };
    float* xA    = alloc_f((size_t)NN*HD);
    float* xB    = alloc_f((size_t)NN*HD);
    float* q0    = alloc_f((size_t)NN*HD);
    float* k0    = alloc_f((size_t)NN*HD);
    float* v0    = alloc_f((size_t)NN*HD);
    float* agg   = alloc_f((size_t)NN*HD);
    float* s_arr = alloc_f((size_t)NE*NH);
    float* rteP  = alloc_f((size_t)MAXL*HD);
    float* Kc    = alloc_f((size_t)MAXL*NT*HD);
    float* Vc    = alloc_f((size_t)MAXL*NT*HD);
    _Float16* kavm = alloc_h((size_t)NN*NR*HD);
    _Float16* kca  = alloc_h((size_t)MAXL*NT*NR*HD);
    _Float16* adaptF = alloc_h((size_t)NT*HD*HD);
    _Float16* qF   = alloc_h((size_t)NL*NT*HD*HD);
    _Float16* kF   = alloc_h((size_t)NL*NT*HD*HD);
    _Float16* vF   = alloc_h((size_t)NL*NT*HD*HD);
    _Float16* aF   = alloc_h((size_t)NL*NT*HD*HD);
    _Float16* relAF = alloc_h((size_t)NL*NR*NH*DKq*DKq);
    _Float16* relMF = alloc_h((size_t)NL*NR*NH*DKq*DKq);
    int* nbucket = alloc_i(NN);
    int* nhist   = alloc_i(HBLK*NT);
    int* nbase   = alloc_i(HBLK*NT);
    int* noff    = alloc_i(8);
    int* cnt     = alloc_i(NN);
    int* bsum    = alloc_i(SCB);
    int* bbase   = alloc_i(SCB);
    int* binCur  = alloc_i(NN);
    int* tgt_off = alloc_i(NN+1);
    int* src_s   = alloc_i(NE);
    int* combo_s = alloc_i(NE);
    int* eid_s   = alloc_i(NE);
    int* tgt_s   = alloc_i(NE);

    float* out_att = (float*)d_out;
    float* out_x   = (float*)d_out + (size_t)NE*NH;

    const dim3 gFoldN(79, NR);
    const dim3 gFoldC(15, NR);
    const int gE256 = (NE + 255)/256;
    const int gNH = (NN*HD + 255)/256;
    const int gSc = (NE + 3)/4;
    const int gSm = (NN*NH + 255)/256;
    const int gAg = (NN + 3)/4;

    // weight pre-pack to f16 fragment-major (once)
    k_w2f16<<<dim3(64, NT),       256,0,stream>>>(adapt_W, adaptF, 8);
    k_w2f16<<<dim3(64, NL*NT),    256,0,stream>>>(q_W, qF, 8);
    k_w2f16<<<dim3(64, NL*NT),    256,0,stream>>>(k_W, kF, 8);
    k_w2f16<<<dim3(64, NL*NT),    256,0,stream>>>(v_W, vF, 8);
    k_w2f16<<<dim3(64, NL*NT),    256,0,stream>>>(a_W, aF, 8);
    k_w2f16<<<dim3(1, NL*NR*NH),  256,0,stream>>>(rel_att, relAF, 5);
    k_w2f16<<<dim3(1, NL*NR*NH),  256,0,stream>>>(rel_msg, relMF, 5);

    // node buckets (by type)
    k_nhist<<<HBLK,256,0,stream>>>(node_type, nhist);
    k_nscan<<<1,64,0,stream>>>(nhist, noff, nbase);
    k_nscatter<<<HBLK,256,0,stream>>>(node_type, nbase, nbucket);

    // edge CSR sorted by tgt (parallel 3-phase scan)
    k_zero_bins<<<SCB,256,0,stream>>>(cnt);
    k_csr_hist<<<gE256,256,0,stream>>>(edge_index, cnt);
    k_scan1<<<SCB,256,0,stream>>>(cnt, tgt_off, bsum);
    k_scan2<<<1,128,0,stream>>>(bsum, bbase, tgt_off);
    k_scan3<<<SCB,256,0,stream>>>(tgt_off, bbase, binCur);
    k_csr_scatter<<<gE256,256,0,stream>>>(edge_index, edge_type, edge_time, node_type,
                                          binCur, src_s, combo_s, eid_s, tgt_s);

    // adapt: x = tanh(node_feature @ adapt_W[t] + b)
    k_typed_mfma<<<TTILES,256,0,stream>>>(node_feature, adaptF, nullptr, nullptr,
                                          adapt_b, nullptr, nullptr,
                                          xA, nullptr, nullptr,
                                          nbucket, noff, 1, 1, nullptr, nullptr);

    const float* x_in = xA;
    float* x_out = xB;
    for (int l = 0; l < NL; l++){
        k_row_gemm<<<dim3(MAXL,1),256,0,stream>>>(rte_emb, rte_W + (size_t)l*HD*HD,
                                                  rte_b + (size_t)l*HD, rteP, HD);
        k_row_gemm<<<dim3(MAXL,NT),256,0,stream>>>(rteP, k_W + (size_t)l*NT*HD*HD, nullptr, Kc, NT*HD);
        k_row_gemm<<<dim3(MAXL,NT),256,0,stream>>>(rteP, v_W + (size_t)l*NT*HD*HD, nullptr, Vc, NT*HD);
        // fused Q/K/V node-level GEMM (MFMA, A-frags in registers)
        k_typed_mfma<<<TTILES,256,0,stream>>>(x_in,
                                              qF + (size_t)l*NT*HD*HD, kF + (size_t)l*NT*HD*HD, vF + (size_t)l*NT*HD*HD,
                                              q_b + (size_t)l*NT*HD,  k_b + (size_t)l*NT*HD,  v_b + (size_t)l*NT*HD,
                                              q0, k0, v0,
                                              nbucket, noff, 3, 0, nullptr, nullptr);
        // fold rel_att into node-level and combo-level tables (MFMA)
        k_fold_mfma<<<gFoldN,256,0,stream>>>(k0, relAF + (size_t)l*NR*NH*1024, (__half*)kavm, NN);
        k_fold_mfma<<<gFoldC,256,0,stream>>>(Kc, relAF + (size_t)l*NR*NH*1024, (__half*)kca, MAXL*NT);
        // scores + softmax
        k_score<<<gSc,256,0,stream>>>(q0, (__half*)kavm, (__half*)kca, rel_pri + (size_t)l*NR*NH,
                                      src_s, combo_s, tgt_s, s_arr);
        const int store_s = (l == NL-1) ? 1 : 0;
        k_softmax<<<gSm,256,0,stream>>>(s_arr, tgt_off, eid_s, out_att, store_s);
        // fold rel_msg, then aggregate (+gelu)
        k_fold_mfma<<<gFoldN,256,0,stream>>>(v0, relMF + (size_t)l*NR*NH*1024, (__half*)kavm, NN);
        k_fold_mfma<<<gFoldC,256,0,stream>>>(Vc, relMF + (size_t)l*NR*NH*1024, (__half*)kca, MAXL*NT);
        k_agg<<<gAg,256,0,stream>>>((__half*)kavm, (__half*)kca, s_arr, tgt_off, src_s, combo_s, agg);
        // output transform + skip
        k_typed_mfma<<<TTILES,256,0,stream>>>(agg, aF + (size_t)l*NT*HD*HD, nullptr, nullptr,
                                              a_b + (size_t)l*NT*HD, nullptr, nullptr,
                                              x_out, nullptr, nullptr,
                                              nbucket, noff, 1, 2, skip + (size_t)l*NT, x_in);
        float* tmp = (float*)x_in; x_in = x_out; x_out = tmp;
    }
    k_copy<<<gNH,256,0,stream>>>(x_in, out_x, NN*HD);
}

// Round 12
// 749.547 us; speedup vs baseline: 1.1377x; 1.1377x over previous
//
#include <hip/hip_runtime.h>
#include <hip/hip_fp16.h>

#define NN    20000
#define NE    150000
#define HD    256
#define NT    4
#define NR    8
#define NH    8
#define DKq   32
#define NL    2
#define MAXL  240
#define HBLK  256
#define SCB   ((NN + 255)/256)
#define RT64  ((NN + 63)/64)          // 313 row tiles
#define TTILES (RT64*NT)              // 1252
#define INV_SQRT_DK 0.17677669529663687f

typedef _Float16 f16x4 __attribute__((ext_vector_type(4)));
typedef float    f32x4v __attribute__((ext_vector_type(4)));

// ---------- node bucketing (by type), block-local histogram ----------
__global__ __launch_bounds__(256) void k_nhist(const int* __restrict__ ntype, int* __restrict__ nhist)
{
    __shared__ int h[NT];
    const int tid = threadIdx.x, b = blockIdx.x;
    if (tid < NT) h[tid] = 0;
    __syncthreads();
    const int cn = (NN + HBLK-1)/HBLK;
    const int nEnd = min((b+1)*cn, NN);
    for (int i = b*cn + tid; i < nEnd; i += 256) atomicAdd(&h[ntype[i]], 1);
    __syncthreads();
    if (tid < NT) nhist[b*NT + tid] = h[tid];
}
__global__ void k_nscan(const int* __restrict__ nhist, int* __restrict__ noff, int* __restrict__ nbase)
{
    __shared__ int tot[NT];
    const int tid = threadIdx.x;
    if (tid < NT){
        int s = 0;
        for (int b = 0; b < HBLK; b++) s += nhist[b*NT + tid];
        tot[tid] = s;
    }
    __syncthreads();
    if (tid == 0){ noff[0]=0; for (int t=0;t<NT;t++) noff[t+1]=noff[t]+tot[t]; }
    if (tid < NT){
        int base = 0; for (int t=0;t<tid;t++) base += tot[t];
        int run = 0;
        for (int b=0;b<HBLK;b++){ nbase[b*NT+tid] = base + run; run += nhist[b*NT+tid]; }
    }
}
__global__ __launch_bounds__(256) void k_nscatter(const int* __restrict__ ntype,
    const int* __restrict__ nbase, int* __restrict__ nbucket)
{
    __shared__ int cur[NT];
    const int tid = threadIdx.x, b = blockIdx.x;
    if (tid < NT) cur[tid] = nbase[b*NT + tid];
    __syncthreads();
    const int cn = (NN + HBLK-1)/HBLK;
    const int nEnd = min((b+1)*cn, NN);
    for (int i = b*cn + tid; i < nEnd; i += 256)
        nbucket[atomicAdd(&cur[ntype[i]], 1)] = i;
}

// ---------- edge CSR build: sort by tgt ----------
__global__ void k_zero_bins(int* __restrict__ cnt){
    int i = blockIdx.x*256 + threadIdx.x;
    if (i < NN) cnt[i] = 0;
}
__global__ void k_csr_hist(const int* __restrict__ ei, int* __restrict__ cnt){
    int e = blockIdx.x*256 + threadIdx.x;
    if (e >= NE) return;
    atomicAdd(&cnt[ei[NE+e]], 1);
}
__global__ __launch_bounds__(256) void k_scan1(const int* __restrict__ cnt,
    int* __restrict__ tgt_off, int* __restrict__ bsum)
{
    __shared__ int sh[256];
    const int t = threadIdx.x, b = blockIdx.x;
    const int i = b*256 + t;
    const int v = (i < NN) ? cnt[i] : 0;
    sh[t] = v;
    __syncthreads();
    #pragma unroll
    for (int d = 1; d < 256; d <<= 1){
        const int u = (t >= d) ? sh[t-d] : 0;
        __syncthreads();
        sh[t] += u;
        __syncthreads();
    }
    if (i < NN) tgt_off[i] = sh[t] - v;
    if (t == 255) bsum[b] = sh[255];
}
__global__ __launch_bounds__(128) void k_scan2(const int* __restrict__ bsum,
    int* __restrict__ bbase, int* __restrict__ tgt_off)
{
    __shared__ int sh[128];
    const int t = threadIdx.x;
    const int v = (t < SCB) ? bsum[t] : 0;
    sh[t] = v;
    __syncthreads();
    #pragma unroll
    for (int d = 1; d < 128; d <<= 1){
        const int u = (t >= d) ? sh[t-d] : 0;
        __syncthreads();
        sh[t] += u;
        __syncthreads();
    }
    if (t < SCB) bbase[t] = sh[t] - v;
    if (t == 0) tgt_off[NN] = NE;
}
__global__ __launch_bounds__(256) void k_scan3(int* __restrict__ tgt_off,
    const int* __restrict__ bbase, int* __restrict__ binCur)
{
    const int i = blockIdx.x*256 + threadIdx.x;
    if (i >= NN) return;
    const int o = tgt_off[i] + bbase[blockIdx.x];
    tgt_off[i] = o;
    binCur[i] = o;
}
__global__ void k_csr_scatter(const int* __restrict__ ei, const int* __restrict__ etype,
    const int* __restrict__ etime, const int* __restrict__ ntype,
    int* __restrict__ binCur, int* __restrict__ src_s, int* __restrict__ combo_s,
    int* __restrict__ eid_s, int* __restrict__ tgt_s)
{
    int e = blockIdx.x*256 + threadIdx.x;
    if (e >= NE) return;
    const int tgt = ei[NE+e], r = etype[e], src = ei[e];
    const int pos = atomicAdd(&binCur[tgt], 1);
    src_s[pos] = src;
    combo_s[pos] = (etime[e]*NT + ntype[src]) | (r << 12);
    eid_s[pos] = e;
    tgt_s[pos] = tgt;
}

// ---------- weight pre-pack: f32 [K][C] -> f16 fragment-major [(k>>2)*C + c][k&3] ----------
__global__ __launch_bounds__(256) void k_w2f16(
    const float* __restrict__ in, _Float16* __restrict__ out, int lc)
{
    const size_t msz = (size_t)gridDim.x * 1024;
    const float* ip = in + (size_t)blockIdx.y * msz;
    _Float16* op = out + (size_t)blockIdx.y * msz;
    const int tid4 = blockIdx.x*256 + threadIdx.x;
    const int C = 1 << lc;
    const int k4 = tid4 >> lc, c = tid4 & (C-1);
    f16x4 hv;
    #pragma unroll
    for (int j = 0; j < 4; j++)
        hv[j] = (_Float16)ip[(size_t)(((k4*4 + j) << lc) + c)];
    *reinterpret_cast<f16x4*>(&op[(size_t)tid4 * 4]) = hv;
}

// ---------- typed MFMA GEMM: wave = 64 rows x 64 cols, 16 simultaneous accumulators ----------
// kc is the OUTER loop: per kc, 4 A-frag LDS reads are shared by 4 col-subtiles (4x less
// LDS traffic than per-cs re-reads), W-frags stream coalesced from frag-major table.
// grid = TTILES (1D). mode 0: bias; 1: tanh; 2: skip-combine.
__global__ __launch_bounds__(256) void k_typed_mfma(
    const float* __restrict__ in,
    const _Float16* __restrict__ W0, const _Float16* __restrict__ W1, const _Float16* __restrict__ W2,
    const float* __restrict__ b0, const float* __restrict__ b1, const float* __restrict__ b2,
    float* __restrict__ o0, float* __restrict__ o1, float* __restrict__ o2,
    const int* __restrict__ nbucket, const int* __restrict__ noff,
    int nsel, int mode, const float* __restrict__ skipv, const float* __restrict__ xold)
{
    const int T = blockIdx.x;
    const int t = T / RT64;
    const int rowTile = T - t*RT64;
    const int start = noff[t], cnt = noff[t+1] - start;
    if (rowTile*64 >= cnt) return;

    const int tid = threadIdx.x;
    const int w = tid >> 6, lane = tid & 63;
    const int lrow = lane & 15, lgrp = lane >> 4;

    __shared__ _Float16 Al[64][260];
    __shared__ int nid[64];

    if (tid < 64){
        const int gr = rowTile*64 + tid;
        nid[tid] = (gr < cnt) ? nbucket[start + gr] : -1;
    }
    __syncthreads();

    // stage A once (f32 -> f16)
    {
        const int arow = nid[tid & 63];
        const int cc0 = (tid >> 6)*64;
        const float* ap = (arow >= 0) ? (in + (size_t)arow*HD + cc0) : nullptr;
        #pragma unroll
        for (int kk = 0; kk < 16; kk++){
            float4 v = make_float4(0.f,0.f,0.f,0.f);
            if (ap) v = *reinterpret_cast<const float4*>(ap + kk*4);
            f16x4 hv;
            hv[0]=(_Float16)v.x; hv[1]=(_Float16)v.y; hv[2]=(_Float16)v.z; hv[3]=(_Float16)v.w;
            *reinterpret_cast<f16x4*>(&Al[tid & 63][cc0 + kk*4]) = hv;
        }
    }
    __syncthreads();

    float sk = 0.f;
    if (mode == 2) sk = 1.f/(1.f + __expf(-skipv[t]));

    auto proc = [&](const _Float16* Wb, const float* bb, float* out){
        const _Float16* W = Wb + (size_t)t*HD*HD;
        const float* bias = bb + (size_t)t*HD;
        f32x4v acc[4][4];   // [cs][rt]
        #pragma unroll
        for (int cs = 0; cs < 4; cs++)
            #pragma unroll
            for (int rt = 0; rt < 4; rt++)
                acc[cs][rt] = (f32x4v){0.f,0.f,0.f,0.f};
        #pragma unroll 4
        for (int kc = 0; kc < 16; kc++){
            f16x4 af[4];
            #pragma unroll
            for (int rt = 0; rt < 4; rt++)
                af[rt] = *reinterpret_cast<const f16x4*>(&Al[rt*16 + lrow][kc*16 + lgrp*4]);
            #pragma unroll
            for (int cs = 0; cs < 4; cs++){
                const f16x4 bf = *reinterpret_cast<const f16x4*>(
                    &W[(size_t)((kc*4 + lgrp)*HD + w*64 + cs*16 + lrow)*4]);
                #pragma unroll
                for (int rt = 0; rt < 4; rt++)
                    acc[cs][rt] = __builtin_amdgcn_mfma_f32_16x16x16f16(af[rt], bf, acc[cs][rt], 0,0,0);
            }
        }
        #pragma unroll
        for (int cs = 0; cs < 4; cs++){
            const int col = w*64 + cs*16 + lrow;
            const float bcol = bias[col];
            #pragma unroll
            for (int rt = 0; rt < 4; rt++){
                #pragma unroll
                for (int i = 0; i < 4; i++){
                    const int lr = rt*16 + lgrp*4 + i;
                    const int gr = rowTile*64 + lr;
                    if (gr >= cnt) continue;
                    const int node = nid[lr];
                    float v = acc[cs][rt][i] + bcol;
                    if (mode == 1) v = tanhf(v);
                    else if (mode == 2){
                        const float xo = xold[(size_t)node*HD + col];
                        v = v*sk + xo*(1.f - sk);
                    }
                    out[(size_t)node*HD + col] = v;
                }
            }
        }
    };

    proc(W0, b0, o0);
    if (nsel > 1){
        proc(W1, b1, o1);
        proc(W2, b2, o2);
    }
}

// ---------- small row GEMM: C[row, ty] = A[row] @ W[ty] (+bias) ----------
__global__ __launch_bounds__(256) void k_row_gemm(
    const float* __restrict__ A, const float* __restrict__ Wb, const float* __restrict__ bias,
    float* __restrict__ C, int c_stride)
{
    const int row = blockIdx.x, ty = blockIdx.y, d = threadIdx.x;
    const float* W = Wb + (size_t)ty*HD*HD;
    __shared__ float ar[HD];
    ar[d] = A[(size_t)row*HD + d];
    __syncthreads();
    float acc = bias ? bias[d] : 0.f;
    #pragma unroll 8
    for (int k=0;k<HD;k++) acc = fmaf(ar[k], W[(size_t)k*HD + d], acc);
    C[(size_t)row*c_stride + ty*HD + d] = acc;
}

// ---------- MFMA fold: OUT[m][r][h*32+c] = sum_d IN[m][h*32+d] * MAT[r][h][d][c] (fp16 out) ----------
__global__ __launch_bounds__(256) void k_fold_mfma(
    const float* __restrict__ IN, const _Float16* __restrict__ MATF,
    __half* __restrict__ OUT, int M)
{
    const int r = blockIdx.y;
    const int lane = threadIdx.x & 63, w = threadIdx.x >> 6;
    const int lrow = lane & 15, lgrp = lane >> 4;
    f16x4 b[NH][2][2];
    const _Float16* Mr = MATF + (size_t)r*NH*1024;
    #pragma unroll
    for (int h = 0; h < NH; h++)
      #pragma unroll
      for (int kb = 0; kb < 2; kb++)
        #pragma unroll
        for (int hf = 0; hf < 2; hf++)
            b[h][kb][hf] = *reinterpret_cast<const f16x4*>(
                &Mr[(size_t)h*1024 + (size_t)(((kb*4 + lgrp)*32) + hf*16 + lrow)*4]);
    const int ntiles = M >> 4;
    for (int t = blockIdx.x*4 + w; t < ntiles; t += gridDim.x*4){
        const int row0 = t*16;
        const float* inrow = IN + (size_t)(row0 + lrow)*HD;
        f16x4 a[NH][2];
        #pragma unroll
        for (int h = 0; h < NH; h++)
          #pragma unroll
          for (int kb = 0; kb < 2; kb++){
              const float4 v = *reinterpret_cast<const float4*>(&inrow[h*32 + kb*16 + lgrp*4]);
              f16x4 aa;
              aa[0]=(_Float16)v.x; aa[1]=(_Float16)v.y; aa[2]=(_Float16)v.z; aa[3]=(_Float16)v.w;
              a[h][kb] = aa;
          }
        #pragma unroll
        for (int h = 0; h < NH; h++){
          #pragma unroll
          for (int hf = 0; hf < 2; hf++){
              f32x4v acc = {0.f,0.f,0.f,0.f};
              acc = __builtin_amdgcn_mfma_f32_16x16x16f16(a[h][0], b[h][0][hf], acc, 0,0,0);
              acc = __builtin_amdgcn_mfma_f32_16x16x16f16(a[h][1], b[h][1][hf], acc, 0,0,0);
              #pragma unroll
              for (int i = 0; i < 4; i++){
                  const int rr = lgrp*4 + i;
                  OUT[((size_t)(row0+rr)*NR + r)*HD + h*32 + hf*16 + lrow] = __float2half(acc[i]);
              }
          }
        }
    }
}

// ---------- edge scores (streaming, wave per edge) ----------
__global__ __launch_bounds__(256) void k_score(
    const float* __restrict__ q0, const __half* __restrict__ kA, const __half* __restrict__ KcA,
    const float* __restrict__ relP,
    const int* __restrict__ src_s, const int* __restrict__ combo_s, const int* __restrict__ tgt_s,
    float* __restrict__ s_arr)
{
    const int j = blockIdx.x*4 + (threadIdx.x >> 6);
    if (j >= NE) return;
    const int lane = threadIdx.x & 63;
    const int h = lane >> 3, c4 = (lane & 7) << 2;
    const int src = src_s[j];
    const int cw  = combo_s[j];
    const int tgt = tgt_s[j];
    const int r = cw >> 12, combo = cw & 0xFFF;

    const float4 q4 = *reinterpret_cast<const float4*>(&q0[(size_t)tgt*HD + h*32 + c4]);
    const __half2* ka = reinterpret_cast<const __half2*>(&kA[((size_t)src*NR + r)*HD + h*32 + c4]);
    const __half2* kc = reinterpret_cast<const __half2*>(&KcA[((size_t)combo*NR + r)*HD + h*32 + c4]);
    const float2 k0f = __half22float2(ka[0]), k1f = __half22float2(ka[1]);
    const float2 c0f = __half22float2(kc[0]), c1f = __half22float2(kc[1]);
    float v = q4.x*(k0f.x+c0f.x) + q4.y*(k0f.y+c0f.y) + q4.z*(k1f.x+c1f.x) + q4.w*(k1f.y+c1f.y);
    v += __shfl_xor(v, 1); v += __shfl_xor(v, 2); v += __shfl_xor(v, 4);
    if ((lane & 7) == 0)
        s_arr[(size_t)j*NH + h] = v * relP[r*NH + h] * INV_SQRT_DK;
}

// ---------- node-parallel segment softmax (CSR) ----------
__global__ __launch_bounds__(256) void k_softmax(
    float* __restrict__ s_arr, const int* __restrict__ tgt_off, const int* __restrict__ eid_s,
    float* __restrict__ out_att, int store)
{
    const int idx = blockIdx.x*256 + threadIdx.x;
    if (idx >= NN*NH) return;
    const int n = idx >> 3, h = idx & 7;
    const int e0 = tgt_off[n], e1 = tgt_off[n+1];
    if (e0 == e1) return;
    float m = -INFINITY;
    for (int j = e0; j < e1; j++) m = fmaxf(m, s_arr[(size_t)j*NH + h]);
    float l = 0.f;
    for (int j = e0; j < e1; j++) l += __expf(s_arr[(size_t)j*NH + h] - m);
    const float inv = 1.f / l;
    for (int j = e0; j < e1; j++){
        const float a = __expf(s_arr[(size_t)j*NH + h] - m) * inv;
        s_arr[(size_t)j*NH + h] = a;
        if (store) out_att[(size_t)eid_s[j]*NH + h] = a;
    }
}

// ---------- aggregation (CSR, wave per node), gelu fused ----------
__global__ __launch_bounds__(256) void k_agg(
    const __half* __restrict__ vM, const __half* __restrict__ VcM,
    const float* __restrict__ alpha,
    const int* __restrict__ tgt_off, const int* __restrict__ src_s, const int* __restrict__ combo_s,
    float* __restrict__ agg)
{
    const int n = blockIdx.x*4 + (threadIdx.x >> 6);
    if (n >= NN) return;
    const int lane = threadIdx.x & 63;
    const int h = lane >> 3, c4 = (lane & 7) << 2;
    const int col = h*32 + c4;
    const int e0 = tgt_off[n], e1 = tgt_off[n+1];
    float a0=0.f, a1=0.f, a2=0.f, a3=0.f;
    for (int j = e0; j < e1; j++){
        const int src = src_s[j];
        const int cw  = combo_s[j];
        const int r = cw >> 12, combo = cw & 0xFFF;
        const float al = alpha[(size_t)j*NH + h];
        const __half2* vm = reinterpret_cast<const __half2*>(&vM[((size_t)src*NR + r)*HD + col]);
        const __half2* vc = reinterpret_cast<const __half2*>(&VcM[((size_t)combo*NR + r)*HD + col]);
        const float2 v0f = __half22float2(vm[0]), v1f = __half22float2(vm[1]);
        const float2 c0f = __half22float2(vc[0]), c1f = __half22float2(vc[1]);
        a0 = fmaf(al, v0f.x + c0f.x, a0);
        a1 = fmaf(al, v0f.y + c0f.y, a1);
        a2 = fmaf(al, v1f.x + c1f.x, a2);
        a3 = fmaf(al, v1f.y + c1f.y, a3);
    }
    float4 o;
    o.x = 0.5f*a0*(1.f + erff(a0*0.70710678118654752f));
    o.y = 0.5f*a1*(1.f + erff(a1*0.70710678118654752f));
    o.z = 0.5f*a2*(1.f + erff(a2*0.70710678118654752f));
    o.w = 0.5f*a3*(1.f + erff(a3*0.70710678118654752f));
    *reinterpret_cast<float4*>(&agg[(size_t)n*HD + col]) = o;
}

__global__ void k_copy(const float* __restrict__ s, float* __restrict__ d, int n){
    int i = blockIdx.x*256 + threadIdx.x;
    if (i < n) d[i] = s[i];
}

extern "C" void kernel_launch(void* const* d_in, const int* in_sizes, int n_in,
                              void* d_out, int out_size, void* d_ws, size_t ws_size,
                              hipStream_t stream)
{
    const float* node_feature = (const float*)d_in[0];
    const int*   node_type    = (const int*)d_in[1];
    const int*   edge_time    = (const int*)d_in[2];
    const int*   edge_index   = (const int*)d_in[3];
    const int*   edge_type    = (const int*)d_in[4];
    const float* adapt_W = (const float*)d_in[5];
    const float* adapt_b = (const float*)d_in[6];
    const float* k_W = (const float*)d_in[7];
    const float* k_b = (const float*)d_in[8];
    const float* q_W = (const float*)d_in[9];
    const float* q_b = (const float*)d_in[10];
    const float* v_W = (const float*)d_in[11];
    const float* v_b = (const float*)d_in[12];
    const float* a_W = (const float*)d_in[13];
    const float* a_b = (const float*)d_in[14];
    const float* rel_pri = (const float*)d_in[15];
    const float* rel_att = (const float*)d_in[16];
    const float* rel_msg = (const float*)d_in[17];
    const float* skip  = (const float*)d_in[18];
    const float* rte_W = (const float*)d_in[19];
    const float* rte_b = (const float*)d_in[20];
    const float* rte_emb = (const float*)d_in[21];

    char* wp = (char*)d_ws;
    auto alloc_f = [&](size_t n)->float*{ float* p=(float*)wp; wp += n*sizeof(float); return p; };
    auto alloc_i = [&](size_t n)->int*  { int*   p=(int*)wp;   wp += n*sizeof(int);   return p; };
    auto alloc_h = [&](size_t n)->_Float16*{ _Float16* p=(_Float16*)wp; wp += n*sizeof(_Float16); return p; };
    float* xA    = alloc_f((size_t)NN*HD);
    float* xB    = alloc_f((size_t)NN*HD);
    float* q0    = alloc_f((size_t)NN*HD);
    float* k0    = alloc_f((size_t)NN*HD);
    float* v0    = alloc_f((size_t)NN*HD);
    float* agg   = alloc_f((size_t)NN*HD);
    float* s_arr = alloc_f((size_t)NE*NH);
    float* rteP  = alloc_f((size_t)MAXL*HD);
    float* Kc    = alloc_f((size_t)MAXL*NT*HD);
    float* Vc    = alloc_f((size_t)MAXL*NT*HD);
    _Float16* kavm = alloc_h((size_t)NN*NR*HD);
    _Float16* kca  = alloc_h((size_t)MAXL*NT*NR*HD);
    _Float16* adaptF = alloc_h((size_t)NT*HD*HD);
    _Float16* qF   = alloc_h((size_t)NL*NT*HD*HD);
    _Float16* kF   = alloc_h((size_t)NL*NT*HD*HD);
    _Float16* vF   = alloc_h((size_t)NL*NT*HD*HD);
    _Float16* aF   = alloc_h((size_t)NL*NT*HD*HD);
    _Float16* relAF = alloc_h((size_t)NL*NR*NH*DKq*DKq);
    _Float16* relMF = alloc_h((size_t)NL*NR*NH*DKq*DKq);
    int* nbucket = alloc_i(NN);
    int* nhist   = alloc_i(HBLK*NT);
    int* nbase   = alloc_i(HBLK*NT);
    int* noff    = alloc_i(8);
    int* cnt     = alloc_i(NN);
    int* bsum    = alloc_i(SCB);
    int* bbase   = alloc_i(SCB);
    int* binCur  = alloc_i(NN);
    int* tgt_off = alloc_i(NN+1);
    int* src_s   = alloc_i(NE);
    int* combo_s = alloc_i(NE);
    int* eid_s   = alloc_i(NE);
    int* tgt_s   = alloc_i(NE);

    float* out_att = (float*)d_out;
    float* out_x   = (float*)d_out + (size_t)NE*NH;

    const dim3 gFoldN(79, NR);
    const dim3 gFoldC(15, NR);
    const int gE256 = (NE + 255)/256;
    const int gNH = (NN*HD + 255)/256;
    const int gSc = (NE + 3)/4;
    const int gSm = (NN*NH + 255)/256;
    const int gAg = (NN + 3)/4;

    // weight pre-pack to f16 fragment-major (once)
    k_w2f16<<<dim3(64, NT),       256,0,stream>>>(adapt_W, adaptF, 8);
    k_w2f16<<<dim3(64, NL*NT),    256,0,stream>>>(q_W, qF, 8);
    k_w2f16<<<dim3(64, NL*NT),    256,0,stream>>>(k_W, kF, 8);
    k_w2f16<<<dim3(64, NL*NT),    256,0,stream>>>(v_W, vF, 8);
    k_w2f16<<<dim3(64, NL*NT),    256,0,stream>>>(a_W, aF, 8);
    k_w2f16<<<dim3(1, NL*NR*NH),  256,0,stream>>>(rel_att, relAF, 5);
    k_w2f16<<<dim3(1, NL*NR*NH),  256,0,stream>>>(rel_msg, relMF, 5);

    // node buckets (by type)
    k_nhist<<<HBLK,256,0,stream>>>(node_type, nhist);
    k_nscan<<<1,64,0,stream>>>(nhist, noff, nbase);
    k_nscatter<<<HBLK,256,0,stream>>>(node_type, nbase, nbucket);

    // edge CSR sorted by tgt (parallel 3-phase scan)
    k_zero_bins<<<SCB,256,0,stream>>>(cnt);
    k_csr_hist<<<gE256,256,0,stream>>>(edge_index, cnt);
    k_scan1<<<SCB,256,0,stream>>>(cnt, tgt_off, bsum);
    k_scan2<<<1,128,0,stream>>>(bsum, bbase, tgt_off);
    k_scan3<<<SCB,256,0,stream>>>(tgt_off, bbase, binCur);
    k_csr_scatter<<<gE256,256,0,stream>>>(edge_index, edge_type, edge_time, node_type,
                                          binCur, src_s, combo_s, eid_s, tgt_s);

    // adapt: x = tanh(node_feature @ adapt_W[t] + b)
    k_typed_mfma<<<TTILES,256,0,stream>>>(node_feature, adaptF, nullptr, nullptr,
                                          adapt_b, nullptr, nullptr,
                                          xA, nullptr, nullptr,
                                          nbucket, noff, 1, 1, nullptr, nullptr);

    const float* x_in = xA;
    float* x_out = xB;
    for (int l = 0; l < NL; l++){
        k_row_gemm<<<dim3(MAXL,1),256,0,stream>>>(rte_emb, rte_W + (size_t)l*HD*HD,
                                                  rte_b + (size_t)l*HD, rteP, HD);
        k_row_gemm<<<dim3(MAXL,NT),256,0,stream>>>(rteP, k_W + (size_t)l*NT*HD*HD, nullptr, Kc, NT*HD);
        k_row_gemm<<<dim3(MAXL,NT),256,0,stream>>>(rteP, v_W + (size_t)l*NT*HD*HD, nullptr, Vc, NT*HD);
        // fused Q/K/V node-level GEMM (MFMA, kc-outer multi-accumulator)
        k_typed_mfma<<<TTILES,256,0,stream>>>(x_in,
                                              qF + (size_t)l*NT*HD*HD, kF + (size_t)l*NT*HD*HD, vF + (size_t)l*NT*HD*HD,
                                              q_b + (size_t)l*NT*HD,  k_b + (size_t)l*NT*HD,  v_b + (size_t)l*NT*HD,
                                              q0, k0, v0,
                                              nbucket, noff, 3, 0, nullptr, nullptr);
        // fold rel_att into node-level and combo-level tables (MFMA)
        k_fold_mfma<<<gFoldN,256,0,stream>>>(k0, relAF + (size_t)l*NR*NH*1024, (__half*)kavm, NN);
        k_fold_mfma<<<gFoldC,256,0,stream>>>(Kc, relAF + (size_t)l*NR*NH*1024, (__half*)kca, MAXL*NT);
        // scores + softmax
        k_score<<<gSc,256,0,stream>>>(q0, (__half*)kavm, (__half*)kca, rel_pri + (size_t)l*NR*NH,
                                      src_s, combo_s, tgt_s, s_arr);
        const int store_s = (l == NL-1) ? 1 : 0;
        k_softmax<<<gSm,256,0,stream>>>(s_arr, tgt_off, eid_s, out_att, store_s);
        // fold rel_msg, then aggregate (+gelu)
        k_fold_mfma<<<gFoldN,256,0,stream>>>(v0, relMF + (size_t)l*NR*NH*1024, (__half*)kavm, NN);
        k_fold_mfma<<<gFoldC,256,0,stream>>>(Vc, relMF + (size_t)l*NR*NH*1024, (__half*)kca, MAXL*NT);
        k_agg<<<gAg,256,0,stream>>>((__half*)kavm, (__half*)kca, s_arr, tgt_off, src_s, combo_s, agg);
        // output transform + skip
        k_typed_mfma<<<TTILES,256,0,stream>>>(agg, aF + (size_t)l*NT*HD*HD, nullptr, nullptr,
                                              a_b + (size_t)l*NT*HD, nullptr, nullptr,
                                              x_out, nullptr, nullptr,
                                              nbucket, noff, 1, 2, skip + (size_t)l*NT, x_in);
        float* tmp = (float*)x_in; x_in = x_out; x_out = tmp;
    }
    k_copy<<<gNH,256,0,stream>>>(x_in, out_x, NN*HD);
}

// Round 13
// 702.295 us; speedup vs baseline: 1.2142x; 1.0673x over previous
//
#include <hip/hip_runtime.h>
#include <hip/hip_fp16.h>

#define NN    20000
#define NE    150000
#define HD    256
#define NT    4
#define NR    8
#define NH    8
#define DKq   32
#define NL    2
#define MAXL  240
#define HBLK  256
#define SCB   ((NN + 255)/256)
#define TMAX  632                     // >= sum_t ceil(cnt_t/32) <= 625+3
#define INV_SQRT_DK 0.17677669529663687f

typedef _Float16 f16x4 __attribute__((ext_vector_type(4)));
typedef float    f32x4v __attribute__((ext_vector_type(4)));

// ---------- node bucketing (by type), block-local histogram ----------
__global__ __launch_bounds__(256) void k_nhist(const int* __restrict__ ntype, int* __restrict__ nhist)
{
    __shared__ int h[NT];
    const int tid = threadIdx.x, b = blockIdx.x;
    if (tid < NT) h[tid] = 0;
    __syncthreads();
    const int cn = (NN + HBLK-1)/HBLK;
    const int nEnd = min((b+1)*cn, NN);
    for (int i = b*cn + tid; i < nEnd; i += 256) atomicAdd(&h[ntype[i]], 1);
    __syncthreads();
    if (tid < NT) nhist[b*NT + tid] = h[tid];
}
__global__ void k_nscan(const int* __restrict__ nhist, int* __restrict__ noff, int* __restrict__ nbase,
                        int* __restrict__ tlist, int* __restrict__ tcount)
{
    __shared__ int tot[NT];
    const int tid = threadIdx.x;
    if (tid < NT){
        int s = 0;
        for (int b = 0; b < HBLK; b++) s += nhist[b*NT + tid];
        tot[tid] = s;
    }
    __syncthreads();
    if (tid == 0){ noff[0]=0; for (int t=0;t<NT;t++) noff[t+1]=noff[t]+tot[t]; }
    if (tid < NT){
        int base = 0; for (int t=0;t<tid;t++) base += tot[t];
        int run = 0;
        for (int b=0;b<HBLK;b++){ nbase[b*NT+tid] = base + run; run += nhist[b*NT+tid]; }
    }
    __syncthreads();
    if (tid == 0){
        int c = 0;
        for (int t = 0; t < NT; t++){
            const int ntile = (tot[t] + 31) >> 5;
            for (int rt = 0; rt < ntile; rt++) tlist[c++] = (t << 20) | rt;
        }
        *tcount = c;
    }
}
__global__ __launch_bounds__(256) void k_nscatter(const int* __restrict__ ntype,
    const int* __restrict__ nbase, int* __restrict__ nbucket)
{
    __shared__ int cur[NT];
    const int tid = threadIdx.x, b = blockIdx.x;
    if (tid < NT) cur[tid] = nbase[b*NT + tid];
    __syncthreads();
    const int cn = (NN + HBLK-1)/HBLK;
    const int nEnd = min((b+1)*cn, NN);
    for (int i = b*cn + tid; i < nEnd; i += 256)
        nbucket[atomicAdd(&cur[ntype[i]], 1)] = i;
}

// ---------- edge CSR build: sort by tgt ----------
__global__ void k_zero_bins(int* __restrict__ cnt){
    int i = blockIdx.x*256 + threadIdx.x;
    if (i < NN) cnt[i] = 0;
}
__global__ void k_csr_hist(const int* __restrict__ ei, int* __restrict__ cnt){
    int e = blockIdx.x*256 + threadIdx.x;
    if (e >= NE) return;
    atomicAdd(&cnt[ei[NE+e]], 1);
}
__global__ __launch_bounds__(256) void k_scan1(const int* __restrict__ cnt,
    int* __restrict__ tgt_off, int* __restrict__ bsum)
{
    __shared__ int sh[256];
    const int t = threadIdx.x, b = blockIdx.x;
    const int i = b*256 + t;
    const int v = (i < NN) ? cnt[i] : 0;
    sh[t] = v;
    __syncthreads();
    #pragma unroll
    for (int d = 1; d < 256; d <<= 1){
        const int u = (t >= d) ? sh[t-d] : 0;
        __syncthreads();
        sh[t] += u;
        __syncthreads();
    }
    if (i < NN) tgt_off[i] = sh[t] - v;
    if (t == 255) bsum[b] = sh[255];
}
__global__ __launch_bounds__(128) void k_scan2(const int* __restrict__ bsum,
    int* __restrict__ bbase, int* __restrict__ tgt_off)
{
    __shared__ int sh[128];
    const int t = threadIdx.x;
    const int v = (t < SCB) ? bsum[t] : 0;
    sh[t] = v;
    __syncthreads();
    #pragma unroll
    for (int d = 1; d < 128; d <<= 1){
        const int u = (t >= d) ? sh[t-d] : 0;
        __syncthreads();
        sh[t] += u;
        __syncthreads();
    }
    if (t < SCB) bbase[t] = sh[t] - v;
    if (t == 0) tgt_off[NN] = NE;
}
__global__ __launch_bounds__(256) void k_scan3(int* __restrict__ tgt_off,
    const int* __restrict__ bbase, int* __restrict__ binCur)
{
    const int i = blockIdx.x*256 + threadIdx.x;
    if (i >= NN) return;
    const int o = tgt_off[i] + bbase[blockIdx.x];
    tgt_off[i] = o;
    binCur[i] = o;
}
__global__ void k_csr_scatter(const int* __restrict__ ei, const int* __restrict__ etype,
    const int* __restrict__ etime, const int* __restrict__ ntype,
    int* __restrict__ binCur, int* __restrict__ src_s, int* __restrict__ combo_s,
    int* __restrict__ eid_s, int* __restrict__ tgt_s)
{
    int e = blockIdx.x*256 + threadIdx.x;
    if (e >= NE) return;
    const int tgt = ei[NE+e], r = etype[e], src = ei[e];
    const int pos = atomicAdd(&binCur[tgt], 1);
    src_s[pos] = src;
    combo_s[pos] = (etime[e]*NT + ntype[src]) | (r << 12);
    eid_s[pos] = e;
    tgt_s[pos] = tgt;
}

// ---------- weight pre-pack: f32 [K][C] -> f16 fragment-major [(k>>2)*C + c][k&3] ----------
__global__ __launch_bounds__(256) void k_w2f16(
    const float* __restrict__ in, _Float16* __restrict__ out, int lc)
{
    const size_t msz = (size_t)gridDim.x * 1024;
    const float* ip = in + (size_t)blockIdx.y * msz;
    _Float16* op = out + (size_t)blockIdx.y * msz;
    const int tid4 = blockIdx.x*256 + threadIdx.x;
    const int C = 1 << lc;
    const int k4 = tid4 >> lc, c = tid4 & (C-1);
    f16x4 hv;
    #pragma unroll
    for (int j = 0; j < 4; j++)
        hv[j] = (_Float16)ip[(size_t)(((k4*4 + j) << lc) + c)];
    *reinterpret_cast<f16x4*>(&op[(size_t)tid4 * 4]) = hv;
}

// ---------- typed MFMA GEMM: 32-row tiles from compact tile list ----------
// grid = TMAX, blocks beyond *tcount exit. Wave w owns cols [w*64,w*64+64) (4 cs).
// Per kc: 2 A-frag LDS reads shared by 4 cs; 4 independent B-loads batched before 8 MFMAs.
__global__ __launch_bounds__(256) void k_typed_mfma(
    const float* __restrict__ in,
    const _Float16* __restrict__ W0, const _Float16* __restrict__ W1, const _Float16* __restrict__ W2,
    const float* __restrict__ b0, const float* __restrict__ b1, const float* __restrict__ b2,
    float* __restrict__ o0, float* __restrict__ o1, float* __restrict__ o2,
    const int* __restrict__ nbucket, const int* __restrict__ noff,
    const int* __restrict__ tlist, const int* __restrict__ tcount,
    int nsel, int mode, const float* __restrict__ skipv, const float* __restrict__ xold)
{
    if ((int)blockIdx.x >= *tcount) return;
    const int ent = tlist[blockIdx.x];
    const int t = ent >> 20, rowTile = ent & 0xFFFFF;
    const int start = noff[t], cnt = noff[t+1] - start;

    const int tid = threadIdx.x;
    const int w = tid >> 6, lane = tid & 63;
    const int lrow = lane & 15, lgrp = lane >> 4;

    __shared__ _Float16 Al[32][260];
    __shared__ int nid[32];

    if (tid < 32){
        const int gr = rowTile*32 + tid;
        nid[tid] = (gr < cnt) ? nbucket[start + gr] : -1;
    }
    __syncthreads();

    // stage A once (f32 -> f16): 8 threads per row, coalesced float4
    {
        const int r = tid >> 3;
        const int arow = nid[r];
        const float* ap = (arow >= 0) ? (in + (size_t)arow*HD) : nullptr;
        #pragma unroll
        for (int j = 0; j < 8; j++){
            const int f4 = (tid & 7) + j*8;
            float4 v = make_float4(0.f,0.f,0.f,0.f);
            if (ap) v = *reinterpret_cast<const float4*>(ap + f4*4);
            f16x4 hv;
            hv[0]=(_Float16)v.x; hv[1]=(_Float16)v.y; hv[2]=(_Float16)v.z; hv[3]=(_Float16)v.w;
            *reinterpret_cast<f16x4*>(&Al[r][f4*4]) = hv;
        }
    }
    __syncthreads();

    float sk = 0.f;
    if (mode == 2) sk = 1.f/(1.f + __expf(-skipv[t]));

    auto proc = [&](const _Float16* Wb, const float* bb, float* out){
        const _Float16* W = Wb + (size_t)t*HD*HD;
        const float* bias = bb + (size_t)t*HD;
        f32x4v acc[4][2];   // [cs][rt]
        #pragma unroll
        for (int cs = 0; cs < 4; cs++){
            acc[cs][0] = (f32x4v){0.f,0.f,0.f,0.f};
            acc[cs][1] = (f32x4v){0.f,0.f,0.f,0.f};
        }
        #pragma unroll 4
        for (int kc = 0; kc < 16; kc++){
            f16x4 bf[4];
            #pragma unroll
            for (int cs = 0; cs < 4; cs++)
                bf[cs] = *reinterpret_cast<const f16x4*>(
                    &W[(size_t)((kc*4 + lgrp)*HD + w*64 + cs*16 + lrow)*4]);
            const f16x4 af0 = *reinterpret_cast<const f16x4*>(&Al[lrow][kc*16 + lgrp*4]);
            const f16x4 af1 = *reinterpret_cast<const f16x4*>(&Al[16 + lrow][kc*16 + lgrp*4]);
            #pragma unroll
            for (int cs = 0; cs < 4; cs++){
                acc[cs][0] = __builtin_amdgcn_mfma_f32_16x16x16f16(af0, bf[cs], acc[cs][0], 0,0,0);
                acc[cs][1] = __builtin_amdgcn_mfma_f32_16x16x16f16(af1, bf[cs], acc[cs][1], 0,0,0);
            }
        }
        #pragma unroll
        for (int cs = 0; cs < 4; cs++){
            const int col = w*64 + cs*16 + lrow;
            const float bcol = bias[col];
            #pragma unroll
            for (int rt = 0; rt < 2; rt++){
                #pragma unroll
                for (int i = 0; i < 4; i++){
                    const int lr = rt*16 + lgrp*4 + i;
                    const int gr = rowTile*32 + lr;
                    if (gr >= cnt) continue;
                    const int node = nid[lr];
                    float v = acc[cs][rt][i] + bcol;
                    if (mode == 1) v = tanhf(v);
                    else if (mode == 2){
                        const float xo = xold[(size_t)node*HD + col];
                        v = v*sk + xo*(1.f - sk);
                    }
                    out[(size_t)node*HD + col] = v;
                }
            }
        }
    };

    proc(W0, b0, o0);
    if (nsel > 1){
        proc(W1, b1, o1);
        proc(W2, b2, o2);
    }
}

// ---------- small row GEMM: C[row, ty] = A[row] @ W[ty] (+bias) ----------
__global__ __launch_bounds__(256) void k_row_gemm(
    const float* __restrict__ A, const float* __restrict__ Wb, const float* __restrict__ bias,
    float* __restrict__ C, int c_stride)
{
    const int row = blockIdx.x, ty = blockIdx.y, d = threadIdx.x;
    const float* W = Wb + (size_t)ty*HD*HD;
    __shared__ float ar[HD];
    ar[d] = A[(size_t)row*HD + d];
    __syncthreads();
    float acc = bias ? bias[d] : 0.f;
    #pragma unroll 8
    for (int k=0;k<HD;k++) acc = fmaf(ar[k], W[(size_t)k*HD + d], acc);
    C[(size_t)row*c_stride + ty*HD + d] = acc;
}

// ---------- MFMA fold: OUT[m][r][h*32+c] = sum_d IN[m][h*32+d] * MAT[r][h][d][c] (fp16 out) ----------
__global__ __launch_bounds__(256) void k_fold_mfma(
    const float* __restrict__ IN, const _Float16* __restrict__ MATF,
    __half* __restrict__ OUT, int M)
{
    const int r = blockIdx.y;
    const int lane = threadIdx.x & 63, w = threadIdx.x >> 6;
    const int lrow = lane & 15, lgrp = lane >> 4;
    f16x4 b[NH][2][2];
    const _Float16* Mr = MATF + (size_t)r*NH*1024;
    #pragma unroll
    for (int h = 0; h < NH; h++)
      #pragma unroll
      for (int kb = 0; kb < 2; kb++)
        #pragma unroll
        for (int hf = 0; hf < 2; hf++)
            b[h][kb][hf] = *reinterpret_cast<const f16x4*>(
                &Mr[(size_t)h*1024 + (size_t)(((kb*4 + lgrp)*32) + hf*16 + lrow)*4]);
    const int ntiles = M >> 4;
    for (int t = blockIdx.x*4 + w; t < ntiles; t += gridDim.x*4){
        const int row0 = t*16;
        const float* inrow = IN + (size_t)(row0 + lrow)*HD;
        f16x4 a[NH][2];
        #pragma unroll
        for (int h = 0; h < NH; h++)
          #pragma unroll
          for (int kb = 0; kb < 2; kb++){
              const float4 v = *reinterpret_cast<const float4*>(&inrow[h*32 + kb*16 + lgrp*4]);
              f16x4 aa;
              aa[0]=(_Float16)v.x; aa[1]=(_Float16)v.y; aa[2]=(_Float16)v.z; aa[3]=(_Float16)v.w;
              a[h][kb] = aa;
          }
        #pragma unroll
        for (int h = 0; h < NH; h++){
          #pragma unroll
          for (int hf = 0; hf < 2; hf++){
              f32x4v acc = {0.f,0.f,0.f,0.f};
              acc = __builtin_amdgcn_mfma_f32_16x16x16f16(a[h][0], b[h][0][hf], acc, 0,0,0);
              acc = __builtin_amdgcn_mfma_f32_16x16x16f16(a[h][1], b[h][1][hf], acc, 0,0,0);
              #pragma unroll
              for (int i = 0; i < 4; i++){
                  const int rr = lgrp*4 + i;
                  OUT[((size_t)(row0+rr)*NR + r)*HD + h*32 + hf*16 + lrow] = __float2half(acc[i]);
              }
          }
        }
    }
}

// ---------- edge scores (streaming, wave per edge) ----------
__global__ __launch_bounds__(256) void k_score(
    const float* __restrict__ q0, const __half* __restrict__ kA, const __half* __restrict__ KcA,
    const float* __restrict__ relP,
    const int* __restrict__ src_s, const int* __restrict__ combo_s, const int* __restrict__ tgt_s,
    float* __restrict__ s_arr)
{
    const int j = blockIdx.x*4 + (threadIdx.x >> 6);
    if (j >= NE) return;
    const int lane = threadIdx.x & 63;
    const int h = lane >> 3, c4 = (lane & 7) << 2;
    const int src = src_s[j];
    const int cw  = combo_s[j];
    const int tgt = tgt_s[j];
    const int r = cw >> 12, combo = cw & 0xFFF;

    const float4 q4 = *reinterpret_cast<const float4*>(&q0[(size_t)tgt*HD + h*32 + c4]);
    const __half2* ka = reinterpret_cast<const __half2*>(&kA[((size_t)src*NR + r)*HD + h*32 + c4]);
    const __half2* kc = reinterpret_cast<const __half2*>(&KcA[((size_t)combo*NR + r)*HD + h*32 + c4]);
    const float2 k0f = __half22float2(ka[0]), k1f = __half22float2(ka[1]);
    const float2 c0f = __half22float2(kc[0]), c1f = __half22float2(kc[1]);
    float v = q4.x*(k0f.x+c0f.x) + q4.y*(k0f.y+c0f.y) + q4.z*(k1f.x+c1f.x) + q4.w*(k1f.y+c1f.y);
    v += __shfl_xor(v, 1); v += __shfl_xor(v, 2); v += __shfl_xor(v, 4);
    if ((lane & 7) == 0)
        s_arr[(size_t)j*NH + h] = v * relP[r*NH + h] * INV_SQRT_DK;
}

// ---------- node-parallel segment softmax (CSR) ----------
__global__ __launch_bounds__(256) void k_softmax(
    float* __restrict__ s_arr, const int* __restrict__ tgt_off, const int* __restrict__ eid_s,
    float* __restrict__ out_att, int store)
{
    const int idx = blockIdx.x*256 + threadIdx.x;
    if (idx >= NN*NH) return;
    const int n = idx >> 3, h = idx & 7;
    const int e0 = tgt_off[n], e1 = tgt_off[n+1];
    if (e0 == e1) return;
    float m = -INFINITY;
    for (int j = e0; j < e1; j++) m = fmaxf(m, s_arr[(size_t)j*NH + h]);
    float l = 0.f;
    for (int j = e0; j < e1; j++) l += __expf(s_arr[(size_t)j*NH + h] - m);
    const float inv = 1.f / l;
    for (int j = e0; j < e1; j++){
        const float a = __expf(s_arr[(size_t)j*NH + h] - m) * inv;
        s_arr[(size_t)j*NH + h] = a;
        if (store) out_att[(size_t)eid_s[j]*NH + h] = a;
    }
}

// ---------- aggregation (CSR, wave per node), gelu fused ----------
__global__ __launch_bounds__(256) void k_agg(
    const __half* __restrict__ vM, const __half* __restrict__ VcM,
    const float* __restrict__ alpha,
    const int* __restrict__ tgt_off, const int* __restrict__ src_s, const int* __restrict__ combo_s,
    float* __restrict__ agg)
{
    const int n = blockIdx.x*4 + (threadIdx.x >> 6);
    if (n >= NN) return;
    const int lane = threadIdx.x & 63;
    const int h = lane >> 3, c4 = (lane & 7) << 2;
    const int col = h*32 + c4;
    const int e0 = tgt_off[n], e1 = tgt_off[n+1];
    float a0=0.f, a1=0.f, a2=0.f, a3=0.f;
    for (int j = e0; j < e1; j++){
        const int src = src_s[j];
        const int cw  = combo_s[j];
        const int r = cw >> 12, combo = cw & 0xFFF;
        const float al = alpha[(size_t)j*NH + h];
        const __half2* vm = reinterpret_cast<const __half2*>(&vM[((size_t)src*NR + r)*HD + col]);
        const __half2* vc = reinterpret_cast<const __half2*>(&VcM[((size_t)combo*NR + r)*HD + col]);
        const float2 v0f = __half22float2(vm[0]), v1f = __half22float2(vm[1]);
        const float2 c0f = __half22float2(vc[0]), c1f = __half22float2(vc[1]);
        a0 = fmaf(al, v0f.x + c0f.x, a0);
        a1 = fmaf(al, v0f.y + c0f.y, a1);
        a2 = fmaf(al, v1f.x + c1f.x, a2);
        a3 = fmaf(al, v1f.y + c1f.y, a3);
    }
    float4 o;
    o.x = 0.5f*a0*(1.f + erff(a0*0.70710678118654752f));
    o.y = 0.5f*a1*(1.f + erff(a1*0.70710678118654752f));
    o.z = 0.5f*a2*(1.f + erff(a2*0.70710678118654752f));
    o.w = 0.5f*a3*(1.f + erff(a3*0.70710678118654752f));
    *reinterpret_cast<float4*>(&agg[(size_t)n*HD + col]) = o;
}

__global__ void k_copy(const float* __restrict__ s, float* __restrict__ d, int n){
    int i = blockIdx.x*256 + threadIdx.x;
    if (i < n) d[i] = s[i];
}

extern "C" void kernel_launch(void* const* d_in, const int* in_sizes, int n_in,
                              void* d_out, int out_size, void* d_ws, size_t ws_size,
                              hipStream_t stream)
{
    const float* node_feature = (const float*)d_in[0];
    const int*   node_type    = (const int*)d_in[1];
    const int*   edge_time    = (const int*)d_in[2];
    const int*   edge_index   = (const int*)d_in[3];
    const int*   edge_type    = (const int*)d_in[4];
    const float* adapt_W = (const float*)d_in[5];
    const float* adapt_b = (const float*)d_in[6];
    const float* k_W = (const float*)d_in[7];
    const float* k_b = (const float*)d_in[8];
    const float* q_W = (const float*)d_in[9];
    const float* q_b = (const float*)d_in[10];
    const float* v_W = (const float*)d_in[11];
    const float* v_b = (const float*)d_in[12];
    const float* a_W = (const float*)d_in[13];
    const float* a_b = (const float*)d_in[14];
    const float* rel_pri = (const float*)d_in[15];
    const float* rel_att = (const float*)d_in[16];
    const float* rel_msg = (const float*)d_in[17];
    const float* skip  = (const float*)d_in[18];
    const float* rte_W = (const float*)d_in[19];
    const float* rte_b = (const float*)d_in[20];
    const float* rte_emb = (const float*)d_in[21];

    char* wp = (char*)d_ws;
    auto alloc_f = [&](size_t n)->float*{ float* p=(float*)wp; wp += n*sizeof(float); return p; };
    auto alloc_i = [&](size_t n)->int*  { int*   p=(int*)wp;   wp += n*sizeof(int);   return p; };
    auto alloc_h = [&](size_t n)->_Float16*{ _Float16* p=(_Float16*)wp; wp += n*sizeof(_Float16); return p; };
    float* xA    = alloc_f((size_t)NN*HD);
    float* xB    = alloc_f((size_t)NN*HD);
    float* q0    = alloc_f((size_t)NN*HD);
    float* k0    = alloc_f((size_t)NN*HD);
    float* v0    = alloc_f((size_t)NN*HD);
    float* agg   = alloc_f((size_t)NN*HD);
    float* s_arr = alloc_f((size_t)NE*NH);
    float* rteP  = alloc_f((size_t)MAXL*HD);
    float* Kc    = alloc_f((size_t)MAXL*NT*HD);
    float* Vc    = alloc_f((size_t)MAXL*NT*HD);
    _Float16* kavm = alloc_h((size_t)NN*NR*HD);
    _Float16* kca  = alloc_h((size_t)MAXL*NT*NR*HD);
    _Float16* adaptF = alloc_h((size_t)NT*HD*HD);
    _Float16* qF   = alloc_h((size_t)NL*NT*HD*HD);
    _Float16* kF   = alloc_h((size_t)NL*NT*HD*HD);
    _Float16* vF   = alloc_h((size_t)NL*NT*HD*HD);
    _Float16* aF   = alloc_h((size_t)NL*NT*HD*HD);
    _Float16* relAF = alloc_h((size_t)NL*NR*NH*DKq*DKq);
    _Float16* relMF = alloc_h((size_t)NL*NR*NH*DKq*DKq);
    int* nbucket = alloc_i(NN);
    int* nhist   = alloc_i(HBLK*NT);
    int* nbase   = alloc_i(HBLK*NT);
    int* noff    = alloc_i(8);
    int* tlist   = alloc_i(TMAX);
    int* tcount  = alloc_i(8);
    int* cnt     = alloc_i(NN);
    int* bsum    = alloc_i(SCB);
    int* bbase   = alloc_i(SCB);
    int* binCur  = alloc_i(NN);
    int* tgt_off = alloc_i(NN+1);
    int* src_s   = alloc_i(NE);
    int* combo_s = alloc_i(NE);
    int* eid_s   = alloc_i(NE);
    int* tgt_s   = alloc_i(NE);

    float* out_att = (float*)d_out;
    float* out_x   = (float*)d_out + (size_t)NE*NH;

    const dim3 gFoldN(79, NR);
    const dim3 gFoldC(15, NR);
    const int gE256 = (NE + 255)/256;
    const int gNH = (NN*HD + 255)/256;
    const int gSc = (NE + 3)/4;
    const int gSm = (NN*NH + 255)/256;
    const int gAg = (NN + 3)/4;

    // weight pre-pack to f16 fragment-major (once)
    k_w2f16<<<dim3(64, NT),       256,0,stream>>>(adapt_W, adaptF, 8);
    k_w2f16<<<dim3(64, NL*NT),    256,0,stream>>>(q_W, qF, 8);
    k_w2f16<<<dim3(64, NL*NT),    256,0,stream>>>(k_W, kF, 8);
    k_w2f16<<<dim3(64, NL*NT),    256,0,stream>>>(v_W, vF, 8);
    k_w2f16<<<dim3(64, NL*NT),    256,0,stream>>>(a_W, aF, 8);
    k_w2f16<<<dim3(1, NL*NR*NH),  256,0,stream>>>(rel_att, relAF, 5);
    k_w2f16<<<dim3(1, NL*NR*NH),  256,0,stream>>>(rel_msg, relMF, 5);

    // node buckets (by type) + compact 32-row tile list
    k_nhist<<<HBLK,256,0,stream>>>(node_type, nhist);
    k_nscan<<<1,64,0,stream>>>(nhist, noff, nbase, tlist, tcount);
    k_nscatter<<<HBLK,256,0,stream>>>(node_type, nbase, nbucket);

    // edge CSR sorted by tgt (parallel 3-phase scan)
    k_zero_bins<<<SCB,256,0,stream>>>(cnt);
    k_csr_hist<<<gE256,256,0,stream>>>(edge_index, cnt);
    k_scan1<<<SCB,256,0,stream>>>(cnt, tgt_off, bsum);
    k_scan2<<<1,128,0,stream>>>(bsum, bbase, tgt_off);
    k_scan3<<<SCB,256,0,stream>>>(tgt_off, bbase, binCur);
    k_csr_scatter<<<gE256,256,0,stream>>>(edge_index, edge_type, edge_time, node_type,
                                          binCur, src_s, combo_s, eid_s, tgt_s);

    // adapt: x = tanh(node_feature @ adapt_W[t] + b)
    k_typed_mfma<<<TMAX,256,0,stream>>>(node_feature, adaptF, nullptr, nullptr,
                                        adapt_b, nullptr, nullptr,
                                        xA, nullptr, nullptr,
                                        nbucket, noff, tlist, tcount, 1, 1, nullptr, nullptr);

    const float* x_in = xA;
    float* x_out = xB;
    for (int l = 0; l < NL; l++){
        k_row_gemm<<<dim3(MAXL,1),256,0,stream>>>(rte_emb, rte_W + (size_t)l*HD*HD,
                                                  rte_b + (size_t)l*HD, rteP, HD);
        k_row_gemm<<<dim3(MAXL,NT),256,0,stream>>>(rteP, k_W + (size_t)l*NT*HD*HD, nullptr, Kc, NT*HD);
        k_row_gemm<<<dim3(MAXL,NT),256,0,stream>>>(rteP, v_W + (size_t)l*NT*HD*HD, nullptr, Vc, NT*HD);
        // fused Q/K/V node-level GEMM
        k_typed_mfma<<<TMAX,256,0,stream>>>(x_in,
                                            qF + (size_t)l*NT*HD*HD, kF + (size_t)l*NT*HD*HD, vF + (size_t)l*NT*HD*HD,
                                            q_b + (size_t)l*NT*HD,  k_b + (size_t)l*NT*HD,  v_b + (size_t)l*NT*HD,
                                            q0, k0, v0,
                                            nbucket, noff, tlist, tcount, 3, 0, nullptr, nullptr);
        // fold rel_att into node-level and combo-level tables (MFMA)
        k_fold_mfma<<<gFoldN,256,0,stream>>>(k0, relAF + (size_t)l*NR*NH*1024, (__half*)kavm, NN);
        k_fold_mfma<<<gFoldC,256,0,stream>>>(Kc, relAF + (size_t)l*NR*NH*1024, (__half*)kca, MAXL*NT);
        // scores + softmax
        k_score<<<gSc,256,0,stream>>>(q0, (__half*)kavm, (__half*)kca, rel_pri + (size_t)l*NR*NH,
                                      src_s, combo_s, tgt_s, s_arr);
        const int store_s = (l == NL-1) ? 1 : 0;
        k_softmax<<<gSm,256,0,stream>>>(s_arr, tgt_off, eid_s, out_att, store_s);
        // fold rel_msg, then aggregate (+gelu)
        k_fold_mfma<<<gFoldN,256,0,stream>>>(v0, relMF + (size_t)l*NR*NH*1024, (__half*)kavm, NN);
        k_fold_mfma<<<gFoldC,256,0,stream>>>(Vc, relMF + (size_t)l*NR*NH*1024, (__half*)kca, MAXL*NT);
        k_agg<<<gAg,256,0,stream>>>((__half*)kavm, (__half*)kca, s_arr, tgt_off, src_s, combo_s, agg);
        // output transform + skip
        k_typed_mfma<<<TMAX,256,0,stream>>>(agg, aF + (size_t)l*NT*HD*HD, nullptr, nullptr,
                                            a_b + (size_t)l*NT*HD, nullptr, nullptr,
                                            x_out, nullptr, nullptr,
                                            nbucket, noff, tlist, tcount, 1, 2, skip + (size_t)l*NT, x_in);
        float* tmp = (float*)x_in; x_in = x_out; x_out = tmp;
    }
    k_copy<<<gNH,256,0,stream>>>(x_in, out_x, NN*HD);
}

// Round 16
// 647.643 us; speedup vs baseline: 1.3167x; 1.0844x over previous
//
#include <hip/hip_runtime.h>
#include <hip/hip_fp16.h>

#define NN    20000
#define NE    150000
#define HD    256
#define NT    4
#define NR    8
#define NH    8
#define DKq   32
#define NL    2
#define MAXL  240
#define HBLK  256
#define SCB   ((NN + 255)/256)
#define TMAX  632
#define INV_SQRT_DK 0.17677669529663687f

typedef _Float16 f16x4 __attribute__((ext_vector_type(4)));
typedef float    f32x4v __attribute__((ext_vector_type(4)));

// ---------- node bucketing (by type) + compact 32-row tile list ----------
__global__ __launch_bounds__(256) void k_nhist(const int* __restrict__ ntype, int* __restrict__ nhist)
{
    __shared__ int h[NT];
    const int tid = threadIdx.x, b = blockIdx.x;
    if (tid < NT) h[tid] = 0;
    __syncthreads();
    const int cn = (NN + HBLK-1)/HBLK;
    const int nEnd = min((b+1)*cn, NN);
    for (int i = b*cn + tid; i < nEnd; i += 256) atomicAdd(&h[ntype[i]], 1);
    __syncthreads();
    if (tid < NT) nhist[b*NT + tid] = h[tid];
}
__global__ void k_nscan(const int* __restrict__ nhist, int* __restrict__ noff, int* __restrict__ nbase,
                        int* __restrict__ tlist, int* __restrict__ tcount)
{
    __shared__ int tot[NT];
    const int tid = threadIdx.x;
    if (tid < NT){
        int s = 0;
        for (int b = 0; b < HBLK; b++) s += nhist[b*NT + tid];
        tot[tid] = s;
    }
    __syncthreads();
    if (tid == 0){ noff[0]=0; for (int t=0;t<NT;t++) noff[t+1]=noff[t]+tot[t]; }
    if (tid < NT){
        int base = 0; for (int t=0;t<tid;t++) base += tot[t];
        int run = 0;
        for (int b=0;b<HBLK;b++){ nbase[b*NT+tid] = base + run; run += nhist[b*NT+tid]; }
    }
    __syncthreads();
    if (tid == 0){
        int c = 0;
        for (int t = 0; t < NT; t++){
            const int ntile = (tot[t] + 31) >> 5;
            for (int rt = 0; rt < ntile; rt++) tlist[c++] = (t << 20) | rt;
        }
        *tcount = c;
    }
}
__global__ __launch_bounds__(256) void k_nscatter(const int* __restrict__ ntype,
    const int* __restrict__ nbase, int* __restrict__ nbucket)
{
    __shared__ int cur[NT];
    const int tid = threadIdx.x, b = blockIdx.x;
    if (tid < NT) cur[tid] = nbase[b*NT + tid];
    __syncthreads();
    const int cn = (NN + HBLK-1)/HBLK;
    const int nEnd = min((b+1)*cn, NN);
    for (int i = b*cn + tid; i < nEnd; i += 256)
        nbucket[atomicAdd(&cur[ntype[i]], 1)] = i;
}

// ---------- edge CSR build: sort by tgt ----------
__global__ void k_zero_bins(int* __restrict__ cnt){
    int i = blockIdx.x*256 + threadIdx.x;
    if (i < NN) cnt[i] = 0;
}
__global__ void k_csr_hist(const int* __restrict__ ei, int* __restrict__ cnt){
    int e = blockIdx.x*256 + threadIdx.x;
    if (e >= NE) return;
    atomicAdd(&cnt[ei[NE+e]], 1);
}
__global__ __launch_bounds__(256) void k_scan1(const int* __restrict__ cnt,
    int* __restrict__ tgt_off, int* __restrict__ bsum)
{
    __shared__ int sh[256];
    const int t = threadIdx.x, b = blockIdx.x;
    const int i = b*256 + t;
    const int v = (i < NN) ? cnt[i] : 0;
    sh[t] = v;
    __syncthreads();
    #pragma unroll
    for (int d = 1; d < 256; d <<= 1){
        const int u = (t >= d) ? sh[t-d] : 0;
        __syncthreads();
        sh[t] += u;
        __syncthreads();
    }
    if (i < NN) tgt_off[i] = sh[t] - v;
    if (t == 255) bsum[b] = sh[255];
}
__global__ __launch_bounds__(128) void k_scan2(const int* __restrict__ bsum,
    int* __restrict__ bbase, int* __restrict__ tgt_off)
{
    __shared__ int sh[128];
    const int t = threadIdx.x;
    const int v = (t < SCB) ? bsum[t] : 0;
    sh[t] = v;
    __syncthreads();
    #pragma unroll
    for (int d = 1; d < 128; d <<= 1){
        const int u = (t >= d) ? sh[t-d] : 0;
        __syncthreads();
        sh[t] += u;
        __syncthreads();
    }
    if (t < SCB) bbase[t] = sh[t] - v;
    if (t == 0) tgt_off[NN] = NE;
}
__global__ __launch_bounds__(256) void k_scan3(int* __restrict__ tgt_off,
    const int* __restrict__ bbase, int* __restrict__ binCur)
{
    const int i = blockIdx.x*256 + threadIdx.x;
    if (i >= NN) return;
    const int o = tgt_off[i] + bbase[blockIdx.x];
    tgt_off[i] = o;
    binCur[i] = o;
}
__global__ void k_csr_scatter(const int* __restrict__ ei, const int* __restrict__ etype,
    const int* __restrict__ etime, const int* __restrict__ ntype,
    int* __restrict__ binCur, int* __restrict__ src_s, int* __restrict__ combo_s,
    int* __restrict__ eid_s, int* __restrict__ tgt_s)
{
    int e = blockIdx.x*256 + threadIdx.x;
    if (e >= NE) return;
    const int tgt = ei[NE+e], r = etype[e], src = ei[e];
    const int pos = atomicAdd(&binCur[tgt], 1);
    src_s[pos] = src;
    combo_s[pos] = (etime[e]*NT + ntype[src]) | (r << 12);
    eid_s[pos] = e;
    tgt_s[pos] = tgt;
}

// ---------- weight pre-pack (merged): 36 big 256x256 mats -> frag-major f16 ----------
__global__ __launch_bounds__(256) void k_w2f16_big(
    const float* __restrict__ adaptW, const float* __restrict__ qW, const float* __restrict__ kW,
    const float* __restrict__ vW, const float* __restrict__ aW, _Float16* __restrict__ out)
{
    const int y = blockIdx.y;
    const float* src; int m;
    if (y < 4){ src = adaptW; m = y; }
    else if (y < 12){ src = qW; m = y-4; }
    else if (y < 20){ src = kW; m = y-12; }
    else if (y < 28){ src = vW; m = y-20; }
    else { src = aW; m = y-28; }
    const float* ip = src + (size_t)m*65536;
    _Float16* op = out + (size_t)y*65536;
    const int tid4 = blockIdx.x*256 + threadIdx.x;
    const int k4 = tid4 >> 8, c = tid4 & 255;
    f16x4 hv;
    #pragma unroll
    for (int j = 0; j < 4; j++)
        hv[j] = (_Float16)ip[(size_t)(((k4*4 + j) << 8) + c)];
    *reinterpret_cast<f16x4*>(&op[(size_t)tid4 * 4]) = hv;
}
// 256 rel 32x32 mats (att then msg) -> frag-major f16
__global__ __launch_bounds__(256) void k_w2f16_rel(
    const float* __restrict__ attW, const float* __restrict__ msgW, _Float16* __restrict__ out)
{
    const int y = blockIdx.y;
    const float* ip = (y < 128) ? (attW + (size_t)y*1024) : (msgW + (size_t)(y-128)*1024);
    _Float16* op = out + (size_t)y*1024;
    const int tid4 = threadIdx.x;
    const int k4 = tid4 >> 5, c = tid4 & 31;    // FIX: 32-col matrix -> shift by 5 (was 3)
    f16x4 hv;
    #pragma unroll
    for (int j = 0; j < 4; j++)
        hv[j] = (_Float16)ip[(size_t)(((k4*4 + j) << 5) + c)];
    *reinterpret_cast<f16x4*>(&op[(size_t)tid4 * 4]) = hv;
}

// ---------- typed MFMA GEMM: 32-row tiles, compact list; per-output dtype bitmask ----------
__global__ __launch_bounds__(256) void k_typed_mfma(
    const float* __restrict__ inF, const _Float16* __restrict__ inH,
    const _Float16* __restrict__ W0, const _Float16* __restrict__ W1, const _Float16* __restrict__ W2,
    const float* __restrict__ b0, const float* __restrict__ b1, const float* __restrict__ b2,
    void* __restrict__ o0, void* __restrict__ o1, void* __restrict__ o2,
    const int* __restrict__ nbucket, const int* __restrict__ noff,
    const int* __restrict__ tlist, const int* __restrict__ tcount,
    int nsel, int mode, int out_half_mask, const float* __restrict__ skipv, const float* __restrict__ xold)
{
    if ((int)blockIdx.x >= *tcount) return;
    const int ent = tlist[blockIdx.x];
    const int t = ent >> 20, rowTile = ent & 0xFFFFF;
    const int start = noff[t], cnt = noff[t+1] - start;

    const int tid = threadIdx.x;
    const int w = tid >> 6, lane = tid & 63;
    const int lrow = lane & 15, lgrp = lane >> 4;

    __shared__ _Float16 Al[32][260];
    __shared__ int nid[32];

    if (tid < 32){
        const int gr = rowTile*32 + tid;
        nid[tid] = (gr < cnt) ? nbucket[start + gr] : -1;
    }
    __syncthreads();

    // stage A once: 8 threads per row
    {
        const int r = tid >> 3;
        const int arow = nid[r];
        if (inH){
            const _Float16* ap = (arow >= 0) ? (inH + (size_t)arow*HD) : nullptr;
            #pragma unroll
            for (int j = 0; j < 8; j++){
                const int f4 = (tid & 7) + j*8;
                f16x4 hv = {0,0,0,0};
                if (ap) hv = *reinterpret_cast<const f16x4*>(ap + f4*4);
                *reinterpret_cast<f16x4*>(&Al[r][f4*4]) = hv;
            }
        } else {
            const float* ap = (arow >= 0) ? (inF + (size_t)arow*HD) : nullptr;
            #pragma unroll
            for (int j = 0; j < 8; j++){
                const int f4 = (tid & 7) + j*8;
                float4 v = make_float4(0.f,0.f,0.f,0.f);
                if (ap) v = *reinterpret_cast<const float4*>(ap + f4*4);
                f16x4 hv;
                hv[0]=(_Float16)v.x; hv[1]=(_Float16)v.y; hv[2]=(_Float16)v.z; hv[3]=(_Float16)v.w;
                *reinterpret_cast<f16x4*>(&Al[r][f4*4]) = hv;
            }
        }
    }
    __syncthreads();

    float sk = 0.f;
    if (mode == 2) sk = 1.f/(1.f + __expf(-skipv[t]));

    auto proc = [&](const _Float16* Wb, const float* bb, void* out, int oh){
        const _Float16* W = Wb + (size_t)t*HD*HD;
        const float* bias = bb + (size_t)t*HD;
        f32x4v acc[4][2];
        #pragma unroll
        for (int cs = 0; cs < 4; cs++){
            acc[cs][0] = (f32x4v){0.f,0.f,0.f,0.f};
            acc[cs][1] = (f32x4v){0.f,0.f,0.f,0.f};
        }
        #pragma unroll 4
        for (int kc = 0; kc < 16; kc++){
            f16x4 bf[4];
            #pragma unroll
            for (int cs = 0; cs < 4; cs++)
                bf[cs] = *reinterpret_cast<const f16x4*>(
                    &W[(size_t)((kc*4 + lgrp)*HD + w*64 + cs*16 + lrow)*4]);
            const f16x4 af0 = *reinterpret_cast<const f16x4*>(&Al[lrow][kc*16 + lgrp*4]);
            const f16x4 af1 = *reinterpret_cast<const f16x4*>(&Al[16 + lrow][kc*16 + lgrp*4]);
            #pragma unroll
            for (int cs = 0; cs < 4; cs++){
                acc[cs][0] = __builtin_amdgcn_mfma_f32_16x16x16f16(af0, bf[cs], acc[cs][0], 0,0,0);
                acc[cs][1] = __builtin_amdgcn_mfma_f32_16x16x16f16(af1, bf[cs], acc[cs][1], 0,0,0);
            }
        }
        #pragma unroll
        for (int cs = 0; cs < 4; cs++){
            const int col = w*64 + cs*16 + lrow;
            const float bcol = bias[col];
            #pragma unroll
            for (int rt = 0; rt < 2; rt++){
                #pragma unroll
                for (int i = 0; i < 4; i++){
                    const int lr = rt*16 + lgrp*4 + i;
                    const int gr = rowTile*32 + lr;
                    if (gr >= cnt) continue;
                    const int node = nid[lr];
                    float v = acc[cs][rt][i] + bcol;
                    if (mode == 1) v = tanhf(v);
                    else if (mode == 2){
                        const float xo = xold[(size_t)node*HD + col];
                        v = v*sk + xo*(1.f - sk);
                    }
                    if (oh) ((_Float16*)out)[(size_t)node*HD + col] = (_Float16)v;
                    else    ((float*)out)[(size_t)node*HD + col] = v;
                }
            }
        }
    };

    proc(W0, b0, o0, out_half_mask & 1);
    if (nsel > 1){
        proc(W1, b1, o1, (out_half_mask >> 1) & 1);
        proc(W2, b2, o2, (out_half_mask >> 2) & 1);
    }
}

// ---------- small row GEMM: C[row, ty] = A[row] @ W[ty] (+bias), f32 or f16 out ----------
__global__ __launch_bounds__(256) void k_row_gemm(
    const float* __restrict__ A, const float* __restrict__ Wb, const float* __restrict__ bias,
    void* __restrict__ C, int c_stride, int out_half)
{
    const int row = blockIdx.x, ty = blockIdx.y, d = threadIdx.x;
    const float* W = Wb + (size_t)ty*HD*HD;
    __shared__ float ar[HD];
    ar[d] = A[(size_t)row*HD + d];
    __syncthreads();
    float acc = bias ? bias[d] : 0.f;
    #pragma unroll 8
    for (int k=0;k<HD;k++) acc = fmaf(ar[k], W[(size_t)k*HD + d], acc);
    if (out_half) ((_Float16*)C)[(size_t)row*c_stride + ty*HD + d] = (_Float16)acc;
    else          ((float*)C)[(size_t)row*c_stride + ty*HD + d] = acc;
}

// ---------- MFMA fold (f16 input): OUT[m][r][h*32+c] = sum_d IN[m][h*32+d]*MAT[r][h][d][c] ----------
__global__ __launch_bounds__(256) void k_fold_mfma(
    const _Float16* __restrict__ IN, const _Float16* __restrict__ MATF,
    _Float16* __restrict__ OUT, int M)
{
    const int r = blockIdx.y;
    const int lane = threadIdx.x & 63, w = threadIdx.x >> 6;
    const int lrow = lane & 15, lgrp = lane >> 4;
    f16x4 b[NH][2][2];
    const _Float16* Mr = MATF + (size_t)r*NH*1024;
    #pragma unroll
    for (int h = 0; h < NH; h++)
      #pragma unroll
      for (int kb = 0; kb < 2; kb++)
        #pragma unroll
        for (int hf = 0; hf < 2; hf++)
            b[h][kb][hf] = *reinterpret_cast<const f16x4*>(
                &Mr[(size_t)h*1024 + (size_t)(((kb*4 + lgrp)*32) + hf*16 + lrow)*4]);
    const int ntiles = M >> 4;
    for (int t = blockIdx.x*4 + w; t < ntiles; t += gridDim.x*4){
        const int row0 = t*16;
        const _Float16* inrow = IN + (size_t)(row0 + lrow)*HD;
        f16x4 a[NH][2];
        #pragma unroll
        for (int h = 0; h < NH; h++)
          #pragma unroll
          for (int kb = 0; kb < 2; kb++)
              a[h][kb] = *reinterpret_cast<const f16x4*>(&inrow[h*32 + kb*16 + lgrp*4]);
        #pragma unroll
        for (int h = 0; h < NH; h++){
          #pragma unroll
          for (int hf = 0; hf < 2; hf++){
              f32x4v acc = {0.f,0.f,0.f,0.f};
              acc = __builtin_amdgcn_mfma_f32_16x16x16f16(a[h][0], b[h][0][hf], acc, 0,0,0);
              acc = __builtin_amdgcn_mfma_f32_16x16x16f16(a[h][1], b[h][1][hf], acc, 0,0,0);
              #pragma unroll
              for (int i = 0; i < 4; i++){
                  const int rr = lgrp*4 + i;
                  OUT[((size_t)(row0+rr)*NR + r)*HD + h*32 + hf*16 + lrow] = (_Float16)acc[i];
              }
          }
        }
    }
}

// ---------- edge scores (streaming, wave per edge; f32 q for softmax precision) ----------
__global__ __launch_bounds__(256) void k_score(
    const float* __restrict__ q0, const _Float16* __restrict__ kA, const _Float16* __restrict__ KcA,
    const float* __restrict__ relP,
    const int* __restrict__ src_s, const int* __restrict__ combo_s, const int* __restrict__ tgt_s,
    float* __restrict__ s_arr)
{
    const int j = blockIdx.x*4 + (threadIdx.x >> 6);
    if (j >= NE) return;
    const int lane = threadIdx.x & 63;
    const int h = lane >> 3, c4 = (lane & 7) << 2;
    const int src = src_s[j];
    const int cw  = combo_s[j];
    const int tgt = tgt_s[j];
    const int r = cw >> 12, combo = cw & 0xFFF;

    const float4 q4 = *reinterpret_cast<const float4*>(&q0[(size_t)tgt*HD + h*32 + c4]);
    const f16x4 ka = *reinterpret_cast<const f16x4*>(&kA[((size_t)src*NR + r)*HD + h*32 + c4]);
    const f16x4 kc = *reinterpret_cast<const f16x4*>(&KcA[((size_t)combo*NR + r)*HD + h*32 + c4]);
    float v = q4.x*((float)ka[0]+(float)kc[0])
            + q4.y*((float)ka[1]+(float)kc[1])
            + q4.z*((float)ka[2]+(float)kc[2])
            + q4.w*((float)ka[3]+(float)kc[3]);
    v += __shfl_xor(v, 1); v += __shfl_xor(v, 2); v += __shfl_xor(v, 4);
    if ((lane & 7) == 0)
        s_arr[(size_t)j*NH + h] = v * relP[r*NH + h] * INV_SQRT_DK;
}

// ---------- node-parallel segment softmax (CSR) ----------
__global__ __launch_bounds__(256) void k_softmax(
    float* __restrict__ s_arr, const int* __restrict__ tgt_off, const int* __restrict__ eid_s,
    float* __restrict__ out_att, int store)
{
    const int idx = blockIdx.x*256 + threadIdx.x;
    if (idx >= NN*NH) return;
    const int n = idx >> 3, h = idx & 7;
    const int e0 = tgt_off[n], e1 = tgt_off[n+1];
    if (e0 == e1) return;
    float m = -INFINITY;
    for (int j = e0; j < e1; j++) m = fmaxf(m, s_arr[(size_t)j*NH + h]);
    float l = 0.f;
    for (int j = e0; j < e1; j++) l += __expf(s_arr[(size_t)j*NH + h] - m);
    const float inv = 1.f / l;
    for (int j = e0; j < e1; j++){
        const float a = __expf(s_arr[(size_t)j*NH + h] - m) * inv;
        s_arr[(size_t)j*NH + h] = a;
        if (store) out_att[(size_t)eid_s[j]*NH + h] = a;
    }
}

// ---------- aggregation (CSR, wave per node), gelu fused, f16 out ----------
__global__ __launch_bounds__(256) void k_agg(
    const _Float16* __restrict__ vM, const _Float16* __restrict__ VcM,
    const float* __restrict__ alpha,
    const int* __restrict__ tgt_off, const int* __restrict__ src_s, const int* __restrict__ combo_s,
    _Float16* __restrict__ agg)
{
    const int n = blockIdx.x*4 + (threadIdx.x >> 6);
    if (n >= NN) return;
    const int lane = threadIdx.x & 63;
    const int h = lane >> 3, c4 = (lane & 7) << 2;
    const int col = h*32 + c4;
    const int e0 = tgt_off[n], e1 = tgt_off[n+1];
    float a0=0.f, a1=0.f, a2=0.f, a3=0.f;
    for (int j = e0; j < e1; j++){
        const int src = src_s[j];
        const int cw  = combo_s[j];
        const int r = cw >> 12, combo = cw & 0xFFF;
        const float al = alpha[(size_t)j*NH + h];
        const f16x4 vm = *reinterpret_cast<const f16x4*>(&vM[((size_t)src*NR + r)*HD + col]);
        const f16x4 vc = *reinterpret_cast<const f16x4*>(&VcM[((size_t)combo*NR + r)*HD + col]);
        a0 = fmaf(al, (float)vm[0] + (float)vc[0], a0);
        a1 = fmaf(al, (float)vm[1] + (float)vc[1], a1);
        a2 = fmaf(al, (float)vm[2] + (float)vc[2], a2);
        a3 = fmaf(al, (float)vm[3] + (float)vc[3], a3);
    }
    f16x4 o;
    o[0] = (_Float16)(0.5f*a0*(1.f + erff(a0*0.70710678118654752f)));
    o[1] = (_Float16)(0.5f*a1*(1.f + erff(a1*0.70710678118654752f)));
    o[2] = (_Float16)(0.5f*a2*(1.f + erff(a2*0.70710678118654752f)));
    o[3] = (_Float16)(0.5f*a3*(1.f + erff(a3*0.70710678118654752f)));
    *reinterpret_cast<f16x4*>(&agg[(size_t)n*HD + col]) = o;
}

__global__ void k_copy(const float* __restrict__ s, float* __restrict__ d, int n){
    int i = blockIdx.x*256 + threadIdx.x;
    if (i < n) d[i] = s[i];
}

extern "C" void kernel_launch(void* const* d_in, const int* in_sizes, int n_in,
                              void* d_out, int out_size, void* d_ws, size_t ws_size,
                              hipStream_t stream)
{
    const float* node_feature = (const float*)d_in[0];
    const int*   node_type    = (const int*)d_in[1];
    const int*   edge_time    = (const int*)d_in[2];
    const int*   edge_index   = (const int*)d_in[3];
    const int*   edge_type    = (const int*)d_in[4];
    const float* adapt_W = (const float*)d_in[5];
    const float* adapt_b = (const float*)d_in[6];
    const float* k_W = (const float*)d_in[7];
    const float* k_b = (const float*)d_in[8];
    const float* q_W = (const float*)d_in[9];
    const float* q_b = (const float*)d_in[10];
    const float* v_W = (const float*)d_in[11];
    const float* v_b = (const float*)d_in[12];
    const float* a_W = (const float*)d_in[13];
    const float* a_b = (const float*)d_in[14];
    const float* rel_pri = (const float*)d_in[15];
    const float* rel_att = (const float*)d_in[16];
    const float* rel_msg = (const float*)d_in[17];
    const float* skip  = (const float*)d_in[18];
    const float* rte_W = (const float*)d_in[19];
    const float* rte_b = (const float*)d_in[20];
    const float* rte_emb = (const float*)d_in[21];

    char* wp = (char*)d_ws;
    auto alloc_f = [&](size_t n)->float*{ float* p=(float*)wp; wp += n*sizeof(float); return p; };
    auto alloc_i = [&](size_t n)->int*  { int*   p=(int*)wp;   wp += n*sizeof(int);   return p; };
    auto alloc_h = [&](size_t n)->_Float16*{ _Float16* p=(_Float16*)wp; wp += n*sizeof(_Float16); return p; };
    float* xA    = alloc_f((size_t)NN*HD);
    float* xB    = alloc_f((size_t)NN*HD);
    float* q0f   = alloc_f((size_t)NN*HD);
    _Float16* k0h = alloc_h((size_t)NN*HD);
    _Float16* v0h = alloc_h((size_t)NN*HD);
    _Float16* aggh= alloc_h((size_t)NN*HD);
    float* s_arr = alloc_f((size_t)NE*NH);
    float* rteP  = alloc_f((size_t)MAXL*HD);
    _Float16* Kch = alloc_h((size_t)MAXL*NT*HD);
    _Float16* Vch = alloc_h((size_t)MAXL*NT*HD);
    _Float16* kavm = alloc_h((size_t)NN*NR*HD);        // kA then reused for vM
    _Float16* kca  = alloc_h((size_t)MAXL*NT*NR*HD);   // KcA then reused for VcM
    _Float16* wF   = alloc_h((size_t)36*65536);        // adapt|q|k|v|a frag-major
    _Float16* relF = alloc_h((size_t)256*1024);        // att(128) | msg(128)
    int* nbucket = alloc_i(NN);
    int* nhist   = alloc_i(HBLK*NT);
    int* nbase   = alloc_i(HBLK*NT);
    int* noff    = alloc_i(8);
    int* tlist   = alloc_i(TMAX);
    int* tcount  = alloc_i(8);
    int* cnt     = alloc_i(NN);
    int* bsum    = alloc_i(SCB);
    int* bbase   = alloc_i(SCB);
    int* binCur  = alloc_i(NN);
    int* tgt_off = alloc_i(NN+1);
    int* src_s   = alloc_i(NE);
    int* combo_s = alloc_i(NE);
    int* eid_s   = alloc_i(NE);
    int* tgt_s   = alloc_i(NE);

    const _Float16* adaptF = wF;
    const _Float16* qF = wF + (size_t)4*65536;
    const _Float16* kF = wF + (size_t)12*65536;
    const _Float16* vF = wF + (size_t)20*65536;
    const _Float16* aF = wF + (size_t)28*65536;
    const _Float16* relAF = relF;
    const _Float16* relMF = relF + (size_t)128*1024;

    float* out_att = (float*)d_out;
    float* out_x   = (float*)d_out + (size_t)NE*NH;

    const dim3 gFoldN(79, NR);
    const dim3 gFoldC(15, NR);
    const int gE256 = (NE + 255)/256;
    const int gNH = (NN*HD + 255)/256;
    const int gSc = (NE + 3)/4;
    const int gSm = (NN*NH + 255)/256;
    const int gAg = (NN + 3)/4;

    // weight pre-pack to f16 fragment-major (2 merged launches)
    k_w2f16_big<<<dim3(64,36),256,0,stream>>>(adapt_W, q_W, k_W, v_W, a_W, wF);
    k_w2f16_rel<<<dim3(1,256),256,0,stream>>>(rel_att, rel_msg, relF);

    // node buckets (by type) + compact 32-row tile list
    k_nhist<<<HBLK,256,0,stream>>>(node_type, nhist);
    k_nscan<<<1,64,0,stream>>>(nhist, noff, nbase, tlist, tcount);
    k_nscatter<<<HBLK,256,0,stream>>>(node_type, nbase, nbucket);

    // edge CSR sorted by tgt
    k_zero_bins<<<SCB,256,0,stream>>>(cnt);
    k_csr_hist<<<gE256,256,0,stream>>>(edge_index, cnt);
    k_scan1<<<SCB,256,0,stream>>>(cnt, tgt_off, bsum);
    k_scan2<<<1,128,0,stream>>>(bsum, bbase, tgt_off);
    k_scan3<<<SCB,256,0,stream>>>(tgt_off, bbase, binCur);
    k_csr_scatter<<<gE256,256,0,stream>>>(edge_index, edge_type, edge_time, node_type,
                                          binCur, src_s, combo_s, eid_s, tgt_s);

    // adapt: x = tanh(node_feature @ adapt_W[t] + b)   (f32 in, f32 out)
    k_typed_mfma<<<TMAX,256,0,stream>>>(node_feature, nullptr, adaptF, nullptr, nullptr,
                                        adapt_b, nullptr, nullptr,
                                        xA, nullptr, nullptr,
                                        nbucket, noff, tlist, tcount, 1, 1, 0, nullptr, nullptr);

    const float* x_in = xA;
    float* x_out = xB;
    for (int l = 0; l < NL; l++){
        k_row_gemm<<<dim3(MAXL,1),256,0,stream>>>(rte_emb, rte_W + (size_t)l*HD*HD,
                                                  rte_b + (size_t)l*HD, rteP, HD, 0);
        k_row_gemm<<<dim3(MAXL,NT),256,0,stream>>>(rteP, k_W + (size_t)l*NT*HD*HD, nullptr, Kch, NT*HD, 1);
        k_row_gemm<<<dim3(MAXL,NT),256,0,stream>>>(rteP, v_W + (size_t)l*NT*HD*HD, nullptr, Vch, NT*HD, 1);
        // fused Q/K/V node-level GEMM: q -> f32 (softmax precision), k/v -> f16
        k_typed_mfma<<<TMAX,256,0,stream>>>(x_in, nullptr,
                                            qF + (size_t)l*NT*HD*HD, kF + (size_t)l*NT*HD*HD, vF + (size_t)l*NT*HD*HD,
                                            q_b + (size_t)l*NT*HD,  k_b + (size_t)l*NT*HD,  v_b + (size_t)l*NT*HD,
                                            q0f, k0h, v0h,
                                            nbucket, noff, tlist, tcount, 3, 0, 6, nullptr, nullptr);
        // fold rel_att into node-level and combo-level tables
        k_fold_mfma<<<gFoldN,256,0,stream>>>(k0h, relAF + (size_t)l*NR*NH*1024, kavm, NN);
        k_fold_mfma<<<gFoldC,256,0,stream>>>(Kch, relAF + (size_t)l*NR*NH*1024, kca, MAXL*NT);
        // scores + softmax
        k_score<<<gSc,256,0,stream>>>(q0f, kavm, kca, rel_pri + (size_t)l*NR*NH,
                                      src_s, combo_s, tgt_s, s_arr);
        const int store_s = (l == NL-1) ? 1 : 0;
        k_softmax<<<gSm,256,0,stream>>>(s_arr, tgt_off, eid_s, out_att, store_s);
        // fold rel_msg, then aggregate (+gelu, f16 out)
        k_fold_mfma<<<gFoldN,256,0,stream>>>(v0h, relMF + (size_t)l*NR*NH*1024, kavm, NN);
        k_fold_mfma<<<gFoldC,256,0,stream>>>(Vch, relMF + (size_t)l*NR*NH*1024, kca, MAXL*NT);
        k_agg<<<gAg,256,0,stream>>>(kavm, kca, s_arr, tgt_off, src_s, combo_s, aggh);
        // output transform + skip (f16 in, f32 out)
        k_typed_mfma<<<TMAX,256,0,stream>>>(nullptr, aggh,
                                            aF + (size_t)l*NT*HD*HD, nullptr, nullptr,
                                            a_b + (size_t)l*NT*HD, nullptr, nullptr,
                                            x_out, nullptr, nullptr,
                                            nbucket, noff, tlist, tcount, 1, 2, 0, skip + (size_t)l*NT, x_in);
        float* tmp = (float*)x_in; x_in = x_out; x_out = tmp;
    }
    k_copy<<<gNH,256,0,stream>>>(x_in, out_x, NN*HD);
}